// Round 4
// baseline (3377.903 us; speedup 1.0000x reference)
//
#include <hip/hip_runtime.h>
#include <math.h>

// ---------------------------------------------------------------------------
// RSSM, Round 7: persistent kernel, nt-PARTITIONED (weights L2-resident).
// R6 post-mortem: row-partition needs all 21MB of weights per XCD per step
// (L2=4MB) -> 2.9GB MALL stream at ~1TB/s = the whole 3.0ms.  Fix: XCD g
// owns output cols nt in [8g,8g+8) of EVERY layer for ALL rows -> 2.6MB
// weight slice per XCD, L2-resident for all 32 steps (no invalidation in
// a persistent kernel).  Cross-XCD activation handoff, fence-free:
//   - producers store activations with relaxed AGENT-scope atomics
//     (sc-bit write-through to MALL; no cache flush instructions),
//   - per-step write-once buffers => consumers can't hold stale lines,
//     plain vector loads miss to MALL = fresh,
//   - hierarchical barrier: intra-XCD counter (local L2) + 8 XCD leaders
//     on one global counter; monotonic, relaxed, no fences.
// 512-thread blocks (8 waves/CU) for 2x memory-level parallelism.
// ---------------------------------------------------------------------------

typedef __attribute__((ext_vector_type(8))) short bf16x8;
typedef __attribute__((ext_vector_type(4))) float f32x4;

#define MFMA(a, b, c) __builtin_amdgcn_mfma_f32_16x16x32_bf16(a, b, c, 0, 0, 0)
#define NBLK 256

__device__ __forceinline__ short f2bf(float f) {
    unsigned u = __float_as_uint(f);
    u += 0x7FFF + ((u >> 16) & 1);   // RNE
    return (short)(u >> 16);
}
__device__ __forceinline__ float sigmoidf_(float x) { return 1.f / (1.f + expf(-x)); }
__device__ __forceinline__ float softplusf_(float x) {
    return fmaxf(x, 0.f) + log1pf(expf(-fabsf(x)));
}
__device__ __forceinline__ f32x4 zero4() { f32x4 v = {0.f, 0.f, 0.f, 0.f}; return v; }

// device-scope (write-through) activation store; relaxed = no fence emitted
__device__ __forceinline__ void stS(short* p, short v) {
    __hip_atomic_store(p, v, __ATOMIC_RELAXED, __HIP_MEMORY_SCOPE_AGENT);
}
__device__ __forceinline__ unsigned ldU(const unsigned* p) {
    return __hip_atomic_load(p, __ATOMIC_RELAXED, __HIP_MEMORY_SCOPE_AGENT);
}

// B-frag pre-swizzle (one wave per 16n x 32k tile)
__global__ __launch_bounds__(256) void k_swizzle(const float* __restrict__ W,
                                                 short* __restrict__ out,
                                                 int KT, int N)
{
    int gw = blockIdx.x * 4 + (threadIdx.x >> 6);
    int lane = threadIdx.x & 63;
    int nt = gw / KT, kt = gw % KT;
    const float* src = W + (size_t)(kt * 32 + (lane >> 4) * 8) * N + nt * 16 + (lane & 15);
    short tmp[8];
#pragma unroll
    for (int j = 0; j < 8; ++j) tmp[j] = f2bf(src[(size_t)j * N]);
    *(bf16x8*)(out + (((size_t)gw * 64 + lane) << 3)) = *(const bf16x8*)tmp;
}

// obs fp32 [32*512*1024] -> bf16
__global__ __launch_bounds__(256) void k_obs2bf(const float* __restrict__ obs,
                                                short* __restrict__ out)
{
    size_t i = ((size_t)blockIdx.x * 256 + threadIdx.x) * 8;
    short tmp[8];
#pragma unroll
    for (int j = 0; j < 8; ++j) tmp[j] = f2bf(obs[i + j]);
    *(bf16x8*)(out + i) = *(const bf16x8*)tmp;
}

// init stateCat[0], belInit, zero barrier region (4096 u32)
__global__ __launch_bounds__(256) void k_init(const float* __restrict__ prev_state,
                                              const float* __restrict__ prev_belief,
                                              short* __restrict__ stateCat0,
                                              short* __restrict__ belInit,
                                              unsigned* __restrict__ bar)
{
    int i = blockIdx.x * 256 + threadIdx.x;
    if (i < 4096) bar[i] = 0u;
    if (i < 262144) {
        int m = i >> 9, c = i & 511;
        stateCat0[i] = f2bf(prev_state[m * 256 + (c & 255)]);
    } else {
        int j = i - 262144;
        belInit[j] = f2bf(prev_belief[j]);
    }
}

__device__ __forceinline__ bf16x8 loadA16(const short* A, int m0, int kelem, int strideElems, int lane) {
    return *(const bf16x8*)(A + (size_t)(m0 + (lane & 15)) * strideElems + kelem + ((lane >> 4) << 3));
}
__device__ __forceinline__ bf16x8 loadB16(const short* Bsw, size_t tileIdx, int lane) {
    return *(const bf16x8*)(Bsw + ((tileIdx * 64 + lane) << 3));
}

// ---------------------------------------------------------------------------
struct RP2 {
    const short *sw_es, *sw_ih, *sw_hh, *sw_ebpo, *sw_ebpr, *sw_spo, *sw_spr;
    const float *Wf_ebpr;
    const float *b_es, *b_ih, *b_hh, *b_ebpo, *b_ebpr, *b_spo, *b_spr;
    const float *prev_belief, *poses, *post_noise, *prior_noise;
    const short *obsBf;
    const short *belInit;
    short *hiddenB, *belB, *hpB, *hqB, *scB;   // per-step buffers
    float *beliefs, *priStates, *priMeans, *priStds, *postStates, *postMeans, *postStds;
    unsigned *bar;  // [0]=rendezvous, [64+g*64]=census, [1024+g*64]=arrive, [2048+g*64]=release, [8]=global
};

// hierarchical barrier: data already drained by __syncthreads (vmcnt 0);
// agent-scope stores are then MALL-visible; counters are monotonic.
__device__ __forceinline__ void hbar(unsigned* bar, unsigned g, unsigned P,
                                     unsigned rank, unsigned* bc)
{
    unsigned c = ++(*bc);
    __syncthreads();
    if (threadIdx.x == 0) {
        unsigned* larr = bar + 1024 + g * 64;
        unsigned* lrel = bar + 2048 + g * 64;
        __hip_atomic_fetch_add(larr, 1u, __ATOMIC_RELAXED, __HIP_MEMORY_SCOPE_AGENT);
        if (rank == 0) {
            while (ldU(larr) < c * P) {}
            __hip_atomic_fetch_add(bar + 8, 1u, __ATOMIC_RELAXED, __HIP_MEMORY_SCOPE_AGENT);
            while (ldU(bar + 8) < c * 8u) {}
            __hip_atomic_store(lrel, c, __ATOMIC_RELAXED, __HIP_MEMORY_SCOPE_AGENT);
        } else {
            while (ldU(lrel) < c) {}
        }
    }
    __syncthreads();
}

__global__ __launch_bounds__(512, 1) void k_rssm3(RP2 p)
{
    int wid = threadIdx.x >> 6;          // 0..7
    int lane = threadIdx.x & 63;
    int q = lane >> 4, cl = lane & 15;

    __shared__ unsigned s_g, s_rank, s_P;
    if (threadIdx.x == 0) {
        unsigned x;
        asm volatile("s_getreg_b32 %0, hwreg(HW_REG_XCC_ID)" : "=s"(x));
        x &= 7u;
        s_g = x;
        s_rank = __hip_atomic_fetch_add(p.bar + 64 + x * 64, 1u,
                                        __ATOMIC_RELAXED, __HIP_MEMORY_SCOPE_AGENT);
    }
    __syncthreads();
    if (threadIdx.x == 0) {
        __hip_atomic_fetch_add(p.bar, 1u, __ATOMIC_RELAXED, __HIP_MEMORY_SCOPE_AGENT);
        while (ldU(p.bar) < NBLK) {}
        s_P = ldU(p.bar + 64 + s_g * 64);
    }
    __syncthreads();
    const unsigned g = s_g, P = s_P, rank = s_rank;
    const unsigned NSLOT = P * 8;
    const unsigned slot = rank * 8 + (unsigned)wid;
    unsigned bc = 0;

#pragma unroll 1
    for (int t = 0; t < 32; ++t) {
        // ---- phase A: hidden = relu(stateCat @ w_es + b)  [256 units/XCD] ----
        {
            const short* sc = p.scB + (size_t)t * 262144;
            short* hid = p.hiddenB + (size_t)t * 524288;
            for (unsigned u = slot; u < 256; u += NSLOT) {
                int mt = (int)(u >> 3), ntl = (int)(u & 7);
                int nt = (int)g * 8 + ntl;
                int m0 = mt * 16;
                f32x4 acc = zero4();
#pragma unroll 4
                for (int kt = 0; kt < 16; ++kt) {
                    bf16x8 a = loadA16(sc, m0, kt * 32, 512, lane);
                    bf16x8 b = loadB16(p.sw_es, (size_t)nt * 16 + kt, lane);
                    acc = MFMA(a, b, acc);
                }
                int n = nt * 16 + cl;
                float bn = p.b_es[n];
#pragma unroll
                for (int i = 0; i < 4; ++i)
                    stS(&hid[(size_t)(m0 + q * 4 + i) * 1024 + n],
                        f2bf(fmaxf(acc[i] + bn, 0.f)));
            }
        }
        hbar(p.bar, g, P, rank, &bc);

        // ---- phase B: GRU  [256 units/XCD] ----
        {
            const short* hid = p.hiddenB + (size_t)t * 524288;
            const short* belPrevBf = t ? p.belB + (size_t)(t - 1) * 524288 : p.belInit;
            const float* Pf32 = t ? (p.beliefs + (size_t)(t - 1) * 524288) : p.prev_belief;
            float* belT = p.beliefs + (size_t)t * 524288;
            short* belCurBf = p.belB + (size_t)t * 524288;
            for (unsigned u = slot; u < 256; u += NSLOT) {
                int mt = (int)(u >> 3), ntl = (int)(u & 7);
                int nt = (int)g * 8 + ntl;
                int m0 = mt * 16;
                f32x4 r = zero4(), z = zero4(), ni = zero4(), nh = zero4();
#pragma unroll 4
                for (int kt = 0; kt < 32; ++kt) {   // hidden @ w_ih
                    bf16x8 a  = loadA16(hid, m0, kt * 32, 1024, lane);
                    bf16x8 br = loadB16(p.sw_ih, (size_t)(0 * 64 + nt) * 32 + kt, lane);
                    bf16x8 bz = loadB16(p.sw_ih, (size_t)(1 * 64 + nt) * 32 + kt, lane);
                    bf16x8 bn = loadB16(p.sw_ih, (size_t)(2 * 64 + nt) * 32 + kt, lane);
                    r = MFMA(a, br, r);
                    z = MFMA(a, bz, z);
                    ni = MFMA(a, bn, ni);
                }
#pragma unroll 4
                for (int kt = 0; kt < 32; ++kt) {   // beliefPrev @ w_hh
                    bf16x8 a  = loadA16(belPrevBf, m0, kt * 32, 1024, lane);
                    bf16x8 br = loadB16(p.sw_hh, (size_t)(0 * 64 + nt) * 32 + kt, lane);
                    bf16x8 bz = loadB16(p.sw_hh, (size_t)(1 * 64 + nt) * 32 + kt, lane);
                    bf16x8 bn = loadB16(p.sw_hh, (size_t)(2 * 64 + nt) * 32 + kt, lane);
                    r = MFMA(a, br, r);
                    z = MFMA(a, bz, z);
                    nh = MFMA(a, bn, nh);
                }
                int n = nt * 16 + cl;
                float bihr = p.b_ih[n] + p.b_hh[n];
                float bihz = p.b_ih[1024 + n] + p.b_hh[1024 + n];
                float bin = p.b_ih[2048 + n], bhn = p.b_hh[2048 + n];
#pragma unroll
                for (int i = 0; i < 4; ++i) {
                    int m = m0 + q * 4 + i;
                    float rr = sigmoidf_(r[i] + bihr);
                    float zz = sigmoidf_(z[i] + bihz);
                    float ng = tanhf(ni[i] + bin + rr * (nh[i] + bhn));
                    float h = Pf32[(size_t)m * 1024 + n];
                    float v = (1.f - zz) * ng + zz * h;
                    belT[(size_t)m * 1024 + n] = v;          // re-read locally only
                    stS(&belCurBf[(size_t)m * 1024 + n], f2bf(v));
                }
            }
        }
        hbar(p.bar, g, P, rank, &bc);

        // ---- phase C: hp (u<256) / hq (u>=256)  [512 units/XCD] ----
        {
            const short* belCur = p.belB + (size_t)t * 524288;
            const short* obsT = p.obsBf + (size_t)t * 524288;
            const float* poseT = p.poses + (size_t)t * 3072;
            short* hp = p.hpB + (size_t)t * 524288;
            short* hq = p.hqB + (size_t)t * 524288;
            for (unsigned u = slot; u < 512; u += NSLOT) {
                unsigned u2 = u & 255;
                int mt = (int)(u2 >> 3), ntl = (int)(u2 & 7);
                int nt = (int)g * 8 + ntl;
                int m0 = mt * 16;
                int n = nt * 16 + cl;
                if (u < 256) {
                    f32x4 acc = zero4();
#pragma unroll 4
                    for (int kt = 0; kt < 32; ++kt) {
                        bf16x8 a = loadA16(belCur, m0, kt * 32, 1024, lane);
                        bf16x8 b = loadB16(p.sw_ebpo, (size_t)nt * 64 + kt, lane);
                        acc = MFMA(a, b, acc);
                    }
#pragma unroll 4
                    for (int kt = 32; kt < 64; ++kt) {
                        bf16x8 a = loadA16(obsT, m0, (kt - 32) * 32, 1024, lane);
                        bf16x8 b = loadB16(p.sw_ebpo, (size_t)nt * 64 + kt, lane);
                        acc = MFMA(a, b, acc);
                    }
                    float bn = p.b_ebpo[n];
#pragma unroll
                    for (int i = 0; i < 4; ++i)
                        stS(&hp[(size_t)(m0 + q * 4 + i) * 1024 + n],
                            f2bf(fmaxf(acc[i] + bn, 0.f)));
                } else {
                    f32x4 acc = zero4();
#pragma unroll 4
                    for (int kt = 0; kt < 32; ++kt) {
                        bf16x8 a = loadA16(belCur, m0, kt * 32, 1024, lane);
                        bf16x8 b = loadB16(p.sw_ebpr, (size_t)nt * 32 + kt, lane);
                        acc = MFMA(a, b, acc);
                    }
                    float bn2 = p.b_ebpr[n];
#pragma unroll
                    for (int i = 0; i < 4; ++i) {
                        int m = m0 + q * 4 + i;
                        float v = acc[i] + bn2;
#pragma unroll
                        for (int pp = 0; pp < 6; ++pp)
                            v += poseT[(size_t)m * 6 + pp] * p.Wf_ebpr[(size_t)(1024 + pp) * 1024 + n];
                        stS(&hq[(size_t)m * 1024 + n], f2bf(fmaxf(v, 0.f)));
                    }
                }
            }
        }
        hbar(p.bar, g, P, rank, &bc);

        // ---- phase D: heads  [128 units/XCD] ----
        {
            const short* hp = p.hpB + (size_t)t * 524288;
            const short* hq = p.hqB + (size_t)t * 524288;
            short* scW = p.scB + (size_t)(t + 1) * 262144;
            for (unsigned u = slot; u < 128; u += NSLOT) {
                int br = (int)(u >> 6);
                int rem = (int)(u & 63);
                int mt = rem >> 1;           // 0..31
                int ctl = rem & 1;           // 0..1
                int ct = (int)g * 2 + ctl;   // 0..15
                int mh = mt * 16;
                const short* A = br ? hq : hp;
                const short* Bsw = br ? p.sw_spr : p.sw_spo;
                const float* bias = br ? p.b_spr : p.b_spo;
                const float* noise = (br ? p.prior_noise : p.post_noise) + (size_t)t * 131072;
                float* mO  = (br ? p.priMeans  : p.postMeans)  + (size_t)t * 131072;
                float* sO  = (br ? p.priStds   : p.postStds)   + (size_t)t * 131072;
                float* stO = (br ? p.priStates : p.postStates) + (size_t)t * 131072;
                int catOff = br ? 256 : 0;
                f32x4 ma = zero4(), sa = zero4();
#pragma unroll 4
                for (int kt = 0; kt < 32; ++kt) {
                    bf16x8 a  = loadA16(A, mh, kt * 32, 1024, lane);
                    bf16x8 bm = loadB16(Bsw, (size_t)ct * 32 + kt, lane);
                    bf16x8 bs = loadB16(Bsw, (size_t)(16 + ct) * 32 + kt, lane);
                    ma = MFMA(a, bm, ma);
                    sa = MFMA(a, bs, sa);
                }
#pragma unroll
                for (int i = 0; i < 4; ++i) {
                    int m = mh + q * 4 + i;
                    int c = ct * 16 + cl;
                    float mean = ma[i] + bias[c];
                    float sd = softplusf_(sa[i] + bias[c + 256]) + 0.1f;
                    float st = mean + sd * noise[(size_t)m * 256 + c];
                    mO[(size_t)m * 256 + c] = mean;
                    sO[(size_t)m * 256 + c] = sd;
                    stO[(size_t)m * 256 + c] = st;
                    stS(&scW[(size_t)m * 512 + catOff + c], f2bf(st));
                }
            }
        }
        hbar(p.bar, g, P, rank, &bc);
    }
}

// ---------------------------------------------------------------------------
// Fallback per-phase kernels (used only if cooperative launch is rejected).
// ---------------------------------------------------------------------------
__global__ __launch_bounds__(256) void k_embed_state(
    const short* __restrict__ A, const short* __restrict__ Bsw,
    const float* __restrict__ bias, short* __restrict__ outBf)
{
    int wid = threadIdx.x >> 6;
    int lane = threadIdx.x & 63;
    int nt = blockIdx.x & 63, mb = blockIdx.x >> 6;
    int m0 = (mb * 4 + wid) * 32;
    f32x4 acc0 = zero4(), acc1 = zero4();
#pragma unroll 4
    for (int kt = 0; kt < 16; ++kt) {
        bf16x8 a0 = loadA16(A, m0,      kt * 32, 512, lane);
        bf16x8 a1 = loadA16(A, m0 + 16, kt * 32, 512, lane);
        bf16x8 b  = loadB16(Bsw, (size_t)nt * 16 + kt, lane);
        acc0 = MFMA(a0, b, acc0);
        acc1 = MFMA(a1, b, acc1);
    }
    int q = lane >> 4, cl = lane & 15;
    int n = nt * 16 + cl;
    float bn = bias[n];
#pragma unroll
    for (int i = 0; i < 4; ++i) {
        int m = m0 + q * 4 + i;
        outBf[(size_t)m * 1024 + n]        = f2bf(fmaxf(acc0[i] + bn, 0.f));
        outBf[(size_t)(m + 16) * 1024 + n] = f2bf(fmaxf(acc1[i] + bn, 0.f));
    }
}

__global__ __launch_bounds__(256) void k_gru(
    const short* __restrict__ Hbf, const short* __restrict__ Pbf,
    const float* __restrict__ Pf32,
    const short* __restrict__ sw_ih, const short* __restrict__ sw_hh,
    const float* __restrict__ b_ih, const float* __restrict__ b_hh,
    float* __restrict__ belF32, short* __restrict__ belBf)
{
    int wid = threadIdx.x >> 6;
    int lane = threadIdx.x & 63;
    int nt = blockIdx.x & 63, mb = blockIdx.x >> 6;
    int m0 = (mb * 4 + wid) * 32;
    f32x4 r0 = zero4(), r1 = zero4(), z0 = zero4(), z1 = zero4();
    f32x4 ni0 = zero4(), ni1 = zero4(), nh0 = zero4(), nh1 = zero4();
#pragma unroll 4
    for (int kt = 0; kt < 32; ++kt) {
        bf16x8 a0 = loadA16(Hbf, m0,      kt * 32, 1024, lane);
        bf16x8 a1 = loadA16(Hbf, m0 + 16, kt * 32, 1024, lane);
        bf16x8 br = loadB16(sw_ih, (size_t)(0 * 64 + nt) * 32 + kt, lane);
        bf16x8 bz = loadB16(sw_ih, (size_t)(1 * 64 + nt) * 32 + kt, lane);
        bf16x8 bn = loadB16(sw_ih, (size_t)(2 * 64 + nt) * 32 + kt, lane);
        r0 = MFMA(a0, br, r0);   r1 = MFMA(a1, br, r1);
        z0 = MFMA(a0, bz, z0);   z1 = MFMA(a1, bz, z1);
        ni0 = MFMA(a0, bn, ni0); ni1 = MFMA(a1, bn, ni1);
    }
#pragma unroll 4
    for (int kt = 0; kt < 32; ++kt) {
        bf16x8 a0 = loadA16(Pbf, m0,      kt * 32, 1024, lane);
        bf16x8 a1 = loadA16(Pbf, m0 + 16, kt * 32, 1024, lane);
        bf16x8 br = loadB16(sw_hh, (size_t)(0 * 64 + nt) * 32 + kt, lane);
        bf16x8 bz = loadB16(sw_hh, (size_t)(1 * 64 + nt) * 32 + kt, lane);
        bf16x8 bn = loadB16(sw_hh, (size_t)(2 * 64 + nt) * 32 + kt, lane);
        r0 = MFMA(a0, br, r0);   r1 = MFMA(a1, br, r1);
        z0 = MFMA(a0, bz, z0);   z1 = MFMA(a1, bz, z1);
        nh0 = MFMA(a0, bn, nh0); nh1 = MFMA(a1, bn, nh1);
    }
    int q = lane >> 4, cl = lane & 15;
    int n = nt * 16 + cl;
    float bihr = b_ih[n] + b_hh[n];
    float bihz = b_ih[1024 + n] + b_hh[1024 + n];
    float bin = b_ih[2048 + n], bhn = b_hh[2048 + n];
#pragma unroll
    for (int f = 0; f < 2; ++f) {
#pragma unroll
        for (int i = 0; i < 4; ++i) {
            int m = m0 + f * 16 + q * 4 + i;
            float rv = f ? r1[i] : r0[i];
            float zv = f ? z1[i] : z0[i];
            float niv = f ? ni1[i] : ni0[i];
            float nhv = f ? nh1[i] : nh0[i];
            float rr = sigmoidf_(rv + bihr);
            float zz = sigmoidf_(zv + bihz);
            float ng = tanhf(niv + bin + rr * (nhv + bhn));
            float h = Pf32[(size_t)m * 1024 + n];
            float v = (1.f - zz) * ng + zz * h;
            belF32[(size_t)m * 1024 + n] = v;
            belBf[(size_t)m * 1024 + n] = f2bf(v);
        }
    }
}

__global__ __launch_bounds__(256) void k_pp(
    const short* __restrict__ Bel, const short* __restrict__ ObsBf,
    const float* __restrict__ Pose,
    const short* __restrict__ sw_ebpo, const short* __restrict__ sw_ebpr,
    const float* __restrict__ Wf_ebpr,
    const float* __restrict__ b_ebpo, const float* __restrict__ b_ebpr,
    short* __restrict__ hpBf, short* __restrict__ hqBf)
{
    int wid = threadIdx.x >> 6;
    int lane = threadIdx.x & 63;
    int q = lane >> 4, cl = lane & 15;
    int b = blockIdx.x;
    if (b < 256) {
        int nt = b & 63, mb = b >> 6;
        int m0 = (mb * 4 + wid) * 32;
        f32x4 acc0 = zero4(), acc1 = zero4();
#pragma unroll 4
        for (int kt = 0; kt < 32; ++kt) {
            bf16x8 a0 = loadA16(Bel, m0,      kt * 32, 1024, lane);
            bf16x8 a1 = loadA16(Bel, m0 + 16, kt * 32, 1024, lane);
            bf16x8 bb = loadB16(sw_ebpo, (size_t)nt * 64 + kt, lane);
            acc0 = MFMA(a0, bb, acc0);
            acc1 = MFMA(a1, bb, acc1);
        }
#pragma unroll 4
        for (int kt = 32; kt < 64; ++kt) {
            bf16x8 a0 = loadA16(ObsBf, m0,      (kt - 32) * 32, 1024, lane);
            bf16x8 a1 = loadA16(ObsBf, m0 + 16, (kt - 32) * 32, 1024, lane);
            bf16x8 bb = loadB16(sw_ebpo, (size_t)nt * 64 + kt, lane);
            acc0 = MFMA(a0, bb, acc0);
            acc1 = MFMA(a1, bb, acc1);
        }
        int n = nt * 16 + cl;
        float bn = b_ebpo[n];
#pragma unroll
        for (int i = 0; i < 4; ++i) {
            int m = m0 + q * 4 + i;
            hpBf[(size_t)m * 1024 + n]        = f2bf(fmaxf(acc0[i] + bn, 0.f));
            hpBf[(size_t)(m + 16) * 1024 + n] = f2bf(fmaxf(acc1[i] + bn, 0.f));
        }
    } else {
        int b2 = b - 256;
        int nt = b2 & 63, mb = b2 >> 6;
        int m0 = (mb * 4 + wid) * 32;
        f32x4 acc0 = zero4(), acc1 = zero4();
#pragma unroll 4
        for (int kt = 0; kt < 32; ++kt) {
            bf16x8 a0 = loadA16(Bel, m0,      kt * 32, 1024, lane);
            bf16x8 a1 = loadA16(Bel, m0 + 16, kt * 32, 1024, lane);
            bf16x8 bb = loadB16(sw_ebpr, (size_t)nt * 32 + kt, lane);
            acc0 = MFMA(a0, bb, acc0);
            acc1 = MFMA(a1, bb, acc1);
        }
        int n = nt * 16 + cl;
        float bn = b_ebpr[n];
#pragma unroll
        for (int f = 0; f < 2; ++f) {
#pragma unroll
            for (int i = 0; i < 4; ++i) {
                int m = m0 + f * 16 + q * 4 + i;
                float v = (f ? acc1[i] : acc0[i]) + bn;
#pragma unroll
                for (int pp = 0; pp < 6; ++pp)
                    v += Pose[(size_t)m * 6 + pp] * Wf_ebpr[(size_t)(1024 + pp) * 1024 + n];
                hqBf[(size_t)m * 1024 + n] = f2bf(fmaxf(v, 0.f));
            }
        }
    }
}

__global__ __launch_bounds__(256) void k_head(
    const short* __restrict__ Hp, const short* __restrict__ Hq,
    const short* __restrict__ sw_spo, const short* __restrict__ sw_spr,
    const float* __restrict__ b_spo, const float* __restrict__ b_spr,
    const float* __restrict__ nPost, const float* __restrict__ nPri,
    float* __restrict__ pM, float* __restrict__ pS, float* __restrict__ pSt,
    float* __restrict__ qM, float* __restrict__ qS, float* __restrict__ qSt,
    short* __restrict__ stateCat)
{
    int gw = blockIdx.x * 4 + (threadIdx.x >> 6);
    int lane = threadIdx.x & 63;
    int br = gw >> 9, rem = gw & 511;
    int mt = rem >> 4, ct = rem & 15;
    int m0 = mt * 16;
    const short* A = br ? Hq : Hp;
    const short* Bsw = br ? sw_spr : sw_spo;
    const float* bias = br ? b_spr : b_spo;
    const float* noise = br ? nPri : nPost;
    float* mO = br ? qM : pM;
    float* sO = br ? qS : pS;
    float* stO = br ? qSt : pSt;
    int catOff = br ? 256 : 0;
    f32x4 ma = zero4(), sa = zero4();
#pragma unroll 4
    for (int kt = 0; kt < 32; ++kt) {
        bf16x8 a = loadA16(A, m0, kt * 32, 1024, lane);
        bf16x8 bm = loadB16(Bsw, (size_t)ct * 32 + kt, lane);
        bf16x8 bs = loadB16(Bsw, (size_t)(16 + ct) * 32 + kt, lane);
        ma = MFMA(a, bm, ma);
        sa = MFMA(a, bs, sa);
    }
    int q = lane >> 4, cl = lane & 15;
#pragma unroll
    for (int i = 0; i < 4; ++i) {
        int m = m0 + q * 4 + i;
        int c = ct * 16 + cl;
        float mean = ma[i] + bias[c];
        float sd = softplusf_(sa[i] + bias[c + 256]) + 0.1f;
        float st = mean + sd * noise[(size_t)m * 256 + c];
        mO[(size_t)m * 256 + c] = mean;
        sO[(size_t)m * 256 + c] = sd;
        stO[(size_t)m * 256 + c] = st;
        stateCat[(size_t)m * 512 + catOff + c] = f2bf(st);
    }
}

// ---------------------------------------------------------------------------
extern "C" void kernel_launch(void* const* d_in, const int* in_sizes, int n_in,
                              void* d_out, int out_size, void* d_ws, size_t ws_size,
                              hipStream_t stream)
{
    const float* prev_state  = (const float*)d_in[0];
    const float* prev_belief = (const float*)d_in[1];
    const float* poses       = (const float*)d_in[2];
    const float* obs         = (const float*)d_in[3];
    const float* post_noise  = (const float*)d_in[4];
    const float* prior_noise = (const float*)d_in[5];
    const float* w_es   = (const float*)d_in[6];
    const float* b_es   = (const float*)d_in[7];
    const float* w_ih   = (const float*)d_in[8];
    const float* w_hh   = (const float*)d_in[9];
    const float* b_ih   = (const float*)d_in[10];
    const float* b_hh   = (const float*)d_in[11];
    const float* w_ebpo = (const float*)d_in[12];
    const float* b_ebpo = (const float*)d_in[13];
    const float* w_spo  = (const float*)d_in[14];
    const float* b_spo  = (const float*)d_in[15];
    const float* w_ebpr = (const float*)d_in[16];
    const float* b_ebpr = (const float*)d_in[17];
    const float* w_spr  = (const float*)d_in[18];
    const float* b_spr  = (const float*)d_in[19];

    float* out = (float*)d_out;
    float* beliefs    = out;
    float* priStates  = out + 16777216;
    float* priMeans   = out + 20971520;
    float* priStds    = out + 25165824;
    float* postStates = out + 29360128;
    float* postMeans  = out + 33554432;
    float* postStds   = out + 37748736;

    short* ws = (short*)d_ws;
    size_t o = 0;
    short* sw_es   = ws + o; o += (size_t)512 * 1024;
    short* sw_ih   = ws + o; o += (size_t)1024 * 3072;
    short* sw_hh   = ws + o; o += (size_t)1024 * 3072;
    short* sw_ebpo = ws + o; o += (size_t)2048 * 1024;
    short* sw_ebpr = ws + o; o += (size_t)1024 * 1024;
    short* sw_spo  = ws + o; o += (size_t)1024 * 512;
    short* sw_spr  = ws + o; o += (size_t)1024 * 512;
    short* obsBf   = ws + o; o += (size_t)32 * 512 * 1024;
    short* hiddenB = ws + o; o += (size_t)32 * 512 * 1024;   // per-step
    short* belInit = ws + o; o += (size_t)512 * 1024;
    short* belB    = ws + o; o += (size_t)32 * 512 * 1024;   // per-step
    short* hpB     = ws + o; o += (size_t)32 * 512 * 1024;   // per-step
    short* hqB     = ws + o; o += (size_t)32 * 512 * 1024;   // per-step
    short* scB     = ws + o; o += (size_t)33 * 512 * 512;    // per-step (t=0..32)
    unsigned* bar  = (unsigned*)(ws + o); o += 8192;         // 4096 u32

    // ---- pre-pass ----
    k_swizzle<<<dim3(256),  dim3(256), 0, stream>>>(w_es,   sw_es,   16, 1024);
    k_swizzle<<<dim3(1536), dim3(256), 0, stream>>>(w_ih,   sw_ih,   32, 3072);
    k_swizzle<<<dim3(1536), dim3(256), 0, stream>>>(w_hh,   sw_hh,   32, 3072);
    k_swizzle<<<dim3(1024), dim3(256), 0, stream>>>(w_ebpo, sw_ebpo, 64, 1024);
    k_swizzle<<<dim3(512),  dim3(256), 0, stream>>>(w_ebpr, sw_ebpr, 32, 1024);
    k_swizzle<<<dim3(256),  dim3(256), 0, stream>>>(w_spo,  sw_spo,  32, 512);
    k_swizzle<<<dim3(256),  dim3(256), 0, stream>>>(w_spr,  sw_spr,  32, 512);
    k_obs2bf<<<dim3(8192), dim3(256), 0, stream>>>(obs, obsBf);
    k_init<<<dim3(3072), dim3(256), 0, stream>>>(prev_state, prev_belief, scB, belInit, bar);

    // ---- persistent kernel: nt-partitioned, weights L2-resident ----
    RP2 rp;
    rp.sw_es = sw_es; rp.sw_ih = sw_ih; rp.sw_hh = sw_hh;
    rp.sw_ebpo = sw_ebpo; rp.sw_ebpr = sw_ebpr; rp.sw_spo = sw_spo; rp.sw_spr = sw_spr;
    rp.Wf_ebpr = w_ebpr;
    rp.b_es = b_es; rp.b_ih = b_ih; rp.b_hh = b_hh;
    rp.b_ebpo = b_ebpo; rp.b_ebpr = b_ebpr; rp.b_spo = b_spo; rp.b_spr = b_spr;
    rp.prev_belief = prev_belief; rp.poses = poses;
    rp.post_noise = post_noise; rp.prior_noise = prior_noise;
    rp.obsBf = obsBf; rp.belInit = belInit;
    rp.hiddenB = hiddenB; rp.belB = belB; rp.hpB = hpB; rp.hqB = hqB; rp.scB = scB;
    rp.beliefs = beliefs;
    rp.priStates = priStates; rp.priMeans = priMeans; rp.priStds = priStds;
    rp.postStates = postStates; rp.postMeans = postMeans; rp.postStds = postStds;
    rp.bar = bar;

    void* kargs[] = { (void*)&rp };
    hipError_t ce = hipLaunchCooperativeKernel(k_rssm3, dim3(NBLK), dim3(512),
                                               kargs, 0u, stream);
    if (ce != hipSuccess) {
        // fallback: per-phase launch loop (proven path), per-step bufs
        for (int t = 0; t < 32; ++t) {
            const short* belPrevBf = t ? belB + (size_t)(t - 1) * 524288 : belInit;
            short* belCurBf = belB + (size_t)t * 524288;
            const float* belPrevF = t ? (beliefs + (size_t)(t - 1) * 524288) : prev_belief;
            float* belT = beliefs + (size_t)t * 524288;
            short* hid = hiddenB + (size_t)t * 524288;
            short* hp = hpB + (size_t)t * 524288;
            short* hq = hqB + (size_t)t * 524288;

            k_embed_state<<<dim3(256), dim3(256), 0, stream>>>(scB + (size_t)t * 262144,
                                                               sw_es, b_es, hid);
            k_gru<<<dim3(256), dim3(256), 0, stream>>>(hid, belPrevBf, belPrevF,
                                                       sw_ih, sw_hh, b_ih, b_hh, belT, belCurBf);
            k_pp<<<dim3(512), dim3(256), 0, stream>>>(belCurBf, obsBf + (size_t)t * 524288,
                                                      poses + (size_t)t * 3072,
                                                      sw_ebpo, sw_ebpr, w_ebpr,
                                                      b_ebpo, b_ebpr, hp, hq);
            k_head<<<dim3(256), dim3(256), 0, stream>>>(hp, hq, sw_spo, sw_spr, b_spo, b_spr,
                                                        post_noise + (size_t)t * 131072,
                                                        prior_noise + (size_t)t * 131072,
                                                        postMeans + (size_t)t * 131072,
                                                        postStds + (size_t)t * 131072,
                                                        postStates + (size_t)t * 131072,
                                                        priMeans + (size_t)t * 131072,
                                                        priStds + (size_t)t * 131072,
                                                        priStates + (size_t)t * 131072,
                                                        scB + (size_t)(t + 1) * 262144);
        }
    }
}

// Round 5
// 3375.570 us; speedup vs baseline: 1.0007x; 1.0007x over previous
//
#include <hip/hip_runtime.h>
#include <math.h>

// ---------------------------------------------------------------------------
// RSSM, Round 7: persistent kernel, nt-PARTITIONED (weights L2-resident).
// R6 post-mortem: row-partition needs all 21MB of weights per XCD per step
// (L2=4MB) -> 2.9GB MALL stream at ~1TB/s = the whole 3.0ms.  Fix: XCD g
// owns output cols nt in [8g,8g+8) of EVERY layer for ALL rows -> 2.6MB
// weight slice per XCD, L2-resident for all 32 steps (no invalidation in
// a persistent kernel).  Cross-XCD activation handoff, fence-free:
//   - producers store activations with relaxed AGENT-scope atomics
//     (sc-bit write-through to MALL; no cache flush instructions),
//   - per-step write-once buffers => consumers can't hold stale lines,
//     plain vector loads miss to MALL = fresh,
//   - hierarchical barrier: intra-XCD counter (local L2) + 8 XCD leaders
//     on one global counter; monotonic, relaxed, no fences.
// 512-thread blocks (8 waves/CU) for 2x memory-level parallelism.
// ---------------------------------------------------------------------------

typedef __attribute__((ext_vector_type(8))) short bf16x8;
typedef __attribute__((ext_vector_type(4))) float f32x4;

#define MFMA(a, b, c) __builtin_amdgcn_mfma_f32_16x16x32_bf16(a, b, c, 0, 0, 0)
#define NBLK 256

__device__ __forceinline__ short f2bf(float f) {
    unsigned u = __float_as_uint(f);
    u += 0x7FFF + ((u >> 16) & 1);   // RNE
    return (short)(u >> 16);
}
__device__ __forceinline__ float sigmoidf_(float x) { return 1.f / (1.f + expf(-x)); }
__device__ __forceinline__ float softplusf_(float x) {
    return fmaxf(x, 0.f) + log1pf(expf(-fabsf(x)));
}
__device__ __forceinline__ f32x4 zero4() { f32x4 v = {0.f, 0.f, 0.f, 0.f}; return v; }

// device-scope (write-through) activation store; relaxed = no fence emitted
__device__ __forceinline__ void stS(short* p, short v) {
    __hip_atomic_store(p, v, __ATOMIC_RELAXED, __HIP_MEMORY_SCOPE_AGENT);
}
__device__ __forceinline__ unsigned ldU(const unsigned* p) {
    return __hip_atomic_load(p, __ATOMIC_RELAXED, __HIP_MEMORY_SCOPE_AGENT);
}

// B-frag pre-swizzle (one wave per 16n x 32k tile)
__global__ __launch_bounds__(256) void k_swizzle(const float* __restrict__ W,
                                                 short* __restrict__ out,
                                                 int KT, int N)
{
    int gw = blockIdx.x * 4 + (threadIdx.x >> 6);
    int lane = threadIdx.x & 63;
    int nt = gw / KT, kt = gw % KT;
    const float* src = W + (size_t)(kt * 32 + (lane >> 4) * 8) * N + nt * 16 + (lane & 15);
    short tmp[8];
#pragma unroll
    for (int j = 0; j < 8; ++j) tmp[j] = f2bf(src[(size_t)j * N]);
    *(bf16x8*)(out + (((size_t)gw * 64 + lane) << 3)) = *(const bf16x8*)tmp;
}

// obs fp32 [32*512*1024] -> bf16
__global__ __launch_bounds__(256) void k_obs2bf(const float* __restrict__ obs,
                                                short* __restrict__ out)
{
    size_t i = ((size_t)blockIdx.x * 256 + threadIdx.x) * 8;
    short tmp[8];
#pragma unroll
    for (int j = 0; j < 8; ++j) tmp[j] = f2bf(obs[i + j]);
    *(bf16x8*)(out + i) = *(const bf16x8*)tmp;
}

// init stateCat[0], belInit, zero barrier region (4096 u32)
__global__ __launch_bounds__(256) void k_init(const float* __restrict__ prev_state,
                                              const float* __restrict__ prev_belief,
                                              short* __restrict__ stateCat0,
                                              short* __restrict__ belInit,
                                              unsigned* __restrict__ bar)
{
    int i = blockIdx.x * 256 + threadIdx.x;
    if (i < 4096) bar[i] = 0u;
    if (i < 262144) {
        int m = i >> 9, c = i & 511;
        stateCat0[i] = f2bf(prev_state[m * 256 + (c & 255)]);
    } else {
        int j = i - 262144;
        belInit[j] = f2bf(prev_belief[j]);
    }
}

__device__ __forceinline__ bf16x8 loadA16(const short* A, int m0, int kelem, int strideElems, int lane) {
    return *(const bf16x8*)(A + (size_t)(m0 + (lane & 15)) * strideElems + kelem + ((lane >> 4) << 3));
}
__device__ __forceinline__ bf16x8 loadB16(const short* Bsw, size_t tileIdx, int lane) {
    return *(const bf16x8*)(Bsw + ((tileIdx * 64 + lane) << 3));
}

// ---------------------------------------------------------------------------
struct RP2 {
    const short *sw_es, *sw_ih, *sw_hh, *sw_ebpo, *sw_ebpr, *sw_spo, *sw_spr;
    const float *Wf_ebpr;
    const float *b_es, *b_ih, *b_hh, *b_ebpo, *b_ebpr, *b_spo, *b_spr;
    const float *prev_belief, *poses, *post_noise, *prior_noise;
    const short *obsBf;
    const short *belInit;
    short *hiddenB, *belB, *hpB, *hqB, *scB;   // per-step buffers
    float *beliefs, *priStates, *priMeans, *priStds, *postStates, *postMeans, *postStds;
    unsigned *bar;  // [0]=rendezvous, [64+g*64]=census, [1024+g*64]=arrive, [2048+g*64]=release, [8]=global
};

// hierarchical barrier: data already drained by __syncthreads (vmcnt 0);
// agent-scope stores are then MALL-visible; counters are monotonic.
__device__ __forceinline__ void hbar(unsigned* bar, unsigned g, unsigned P,
                                     unsigned rank, unsigned* bc)
{
    unsigned c = ++(*bc);
    __syncthreads();
    if (threadIdx.x == 0) {
        unsigned* larr = bar + 1024 + g * 64;
        unsigned* lrel = bar + 2048 + g * 64;
        __hip_atomic_fetch_add(larr, 1u, __ATOMIC_RELAXED, __HIP_MEMORY_SCOPE_AGENT);
        if (rank == 0) {
            while (ldU(larr) < c * P) {}
            __hip_atomic_fetch_add(bar + 8, 1u, __ATOMIC_RELAXED, __HIP_MEMORY_SCOPE_AGENT);
            while (ldU(bar + 8) < c * 8u) {}
            __hip_atomic_store(lrel, c, __ATOMIC_RELAXED, __HIP_MEMORY_SCOPE_AGENT);
        } else {
            while (ldU(lrel) < c) {}
        }
    }
    __syncthreads();
}

__global__ __launch_bounds__(512, 1) void k_rssm3(RP2 p)
{
    int wid = threadIdx.x >> 6;          // 0..7
    int lane = threadIdx.x & 63;
    int q = lane >> 4, cl = lane & 15;

    __shared__ unsigned s_g, s_rank, s_P;
    if (threadIdx.x == 0) {
        unsigned x;
        asm volatile("s_getreg_b32 %0, hwreg(HW_REG_XCC_ID)" : "=s"(x));
        x &= 7u;
        s_g = x;
        s_rank = __hip_atomic_fetch_add(p.bar + 64 + x * 64, 1u,
                                        __ATOMIC_RELAXED, __HIP_MEMORY_SCOPE_AGENT);
    }
    __syncthreads();
    if (threadIdx.x == 0) {
        __hip_atomic_fetch_add(p.bar, 1u, __ATOMIC_RELAXED, __HIP_MEMORY_SCOPE_AGENT);
        while (ldU(p.bar) < NBLK) {}
        s_P = ldU(p.bar + 64 + s_g * 64);
    }
    __syncthreads();
    const unsigned g = s_g, P = s_P, rank = s_rank;
    const unsigned NSLOT = P * 8;
    const unsigned slot = rank * 8 + (unsigned)wid;
    unsigned bc = 0;

#pragma unroll 1
    for (int t = 0; t < 32; ++t) {
        // ---- phase A: hidden = relu(stateCat @ w_es + b)  [256 units/XCD] ----
        {
            const short* sc = p.scB + (size_t)t * 262144;
            short* hid = p.hiddenB + (size_t)t * 524288;
            for (unsigned u = slot; u < 256; u += NSLOT) {
                int mt = (int)(u >> 3), ntl = (int)(u & 7);
                int nt = (int)g * 8 + ntl;
                int m0 = mt * 16;
                f32x4 acc = zero4();
#pragma unroll 4
                for (int kt = 0; kt < 16; ++kt) {
                    bf16x8 a = loadA16(sc, m0, kt * 32, 512, lane);
                    bf16x8 b = loadB16(p.sw_es, (size_t)nt * 16 + kt, lane);
                    acc = MFMA(a, b, acc);
                }
                int n = nt * 16 + cl;
                float bn = p.b_es[n];
#pragma unroll
                for (int i = 0; i < 4; ++i)
                    stS(&hid[(size_t)(m0 + q * 4 + i) * 1024 + n],
                        f2bf(fmaxf(acc[i] + bn, 0.f)));
            }
        }
        hbar(p.bar, g, P, rank, &bc);

        // ---- phase B: GRU  [256 units/XCD] ----
        {
            const short* hid = p.hiddenB + (size_t)t * 524288;
            const short* belPrevBf = t ? p.belB + (size_t)(t - 1) * 524288 : p.belInit;
            const float* Pf32 = t ? (p.beliefs + (size_t)(t - 1) * 524288) : p.prev_belief;
            float* belT = p.beliefs + (size_t)t * 524288;
            short* belCurBf = p.belB + (size_t)t * 524288;
            for (unsigned u = slot; u < 256; u += NSLOT) {
                int mt = (int)(u >> 3), ntl = (int)(u & 7);
                int nt = (int)g * 8 + ntl;
                int m0 = mt * 16;
                f32x4 r = zero4(), z = zero4(), ni = zero4(), nh = zero4();
#pragma unroll 4
                for (int kt = 0; kt < 32; ++kt) {   // hidden @ w_ih
                    bf16x8 a  = loadA16(hid, m0, kt * 32, 1024, lane);
                    bf16x8 br = loadB16(p.sw_ih, (size_t)(0 * 64 + nt) * 32 + kt, lane);
                    bf16x8 bz = loadB16(p.sw_ih, (size_t)(1 * 64 + nt) * 32 + kt, lane);
                    bf16x8 bn = loadB16(p.sw_ih, (size_t)(2 * 64 + nt) * 32 + kt, lane);
                    r = MFMA(a, br, r);
                    z = MFMA(a, bz, z);
                    ni = MFMA(a, bn, ni);
                }
#pragma unroll 4
                for (int kt = 0; kt < 32; ++kt) {   // beliefPrev @ w_hh
                    bf16x8 a  = loadA16(belPrevBf, m0, kt * 32, 1024, lane);
                    bf16x8 br = loadB16(p.sw_hh, (size_t)(0 * 64 + nt) * 32 + kt, lane);
                    bf16x8 bz = loadB16(p.sw_hh, (size_t)(1 * 64 + nt) * 32 + kt, lane);
                    bf16x8 bn = loadB16(p.sw_hh, (size_t)(2 * 64 + nt) * 32 + kt, lane);
                    r = MFMA(a, br, r);
                    z = MFMA(a, bz, z);
                    nh = MFMA(a, bn, nh);
                }
                int n = nt * 16 + cl;
                float bihr = p.b_ih[n] + p.b_hh[n];
                float bihz = p.b_ih[1024 + n] + p.b_hh[1024 + n];
                float bin = p.b_ih[2048 + n], bhn = p.b_hh[2048 + n];
#pragma unroll
                for (int i = 0; i < 4; ++i) {
                    int m = m0 + q * 4 + i;
                    float rr = sigmoidf_(r[i] + bihr);
                    float zz = sigmoidf_(z[i] + bihz);
                    float ng = tanhf(ni[i] + bin + rr * (nh[i] + bhn));
                    float h = Pf32[(size_t)m * 1024 + n];
                    float v = (1.f - zz) * ng + zz * h;
                    belT[(size_t)m * 1024 + n] = v;          // re-read locally only
                    stS(&belCurBf[(size_t)m * 1024 + n], f2bf(v));
                }
            }
        }
        hbar(p.bar, g, P, rank, &bc);

        // ---- phase C: hp (u<256) / hq (u>=256)  [512 units/XCD] ----
        {
            const short* belCur = p.belB + (size_t)t * 524288;
            const short* obsT = p.obsBf + (size_t)t * 524288;
            const float* poseT = p.poses + (size_t)t * 3072;
            short* hp = p.hpB + (size_t)t * 524288;
            short* hq = p.hqB + (size_t)t * 524288;
            for (unsigned u = slot; u < 512; u += NSLOT) {
                unsigned u2 = u & 255;
                int mt = (int)(u2 >> 3), ntl = (int)(u2 & 7);
                int nt = (int)g * 8 + ntl;
                int m0 = mt * 16;
                int n = nt * 16 + cl;
                if (u < 256) {
                    f32x4 acc = zero4();
#pragma unroll 4
                    for (int kt = 0; kt < 32; ++kt) {
                        bf16x8 a = loadA16(belCur, m0, kt * 32, 1024, lane);
                        bf16x8 b = loadB16(p.sw_ebpo, (size_t)nt * 64 + kt, lane);
                        acc = MFMA(a, b, acc);
                    }
#pragma unroll 4
                    for (int kt = 32; kt < 64; ++kt) {
                        bf16x8 a = loadA16(obsT, m0, (kt - 32) * 32, 1024, lane);
                        bf16x8 b = loadB16(p.sw_ebpo, (size_t)nt * 64 + kt, lane);
                        acc = MFMA(a, b, acc);
                    }
                    float bn = p.b_ebpo[n];
#pragma unroll
                    for (int i = 0; i < 4; ++i)
                        stS(&hp[(size_t)(m0 + q * 4 + i) * 1024 + n],
                            f2bf(fmaxf(acc[i] + bn, 0.f)));
                } else {
                    f32x4 acc = zero4();
#pragma unroll 4
                    for (int kt = 0; kt < 32; ++kt) {
                        bf16x8 a = loadA16(belCur, m0, kt * 32, 1024, lane);
                        bf16x8 b = loadB16(p.sw_ebpr, (size_t)nt * 32 + kt, lane);
                        acc = MFMA(a, b, acc);
                    }
                    float bn2 = p.b_ebpr[n];
#pragma unroll
                    for (int i = 0; i < 4; ++i) {
                        int m = m0 + q * 4 + i;
                        float v = acc[i] + bn2;
#pragma unroll
                        for (int pp = 0; pp < 6; ++pp)
                            v += poseT[(size_t)m * 6 + pp] * p.Wf_ebpr[(size_t)(1024 + pp) * 1024 + n];
                        stS(&hq[(size_t)m * 1024 + n], f2bf(fmaxf(v, 0.f)));
                    }
                }
            }
        }
        hbar(p.bar, g, P, rank, &bc);

        // ---- phase D: heads  [128 units/XCD] ----
        {
            const short* hp = p.hpB + (size_t)t * 524288;
            const short* hq = p.hqB + (size_t)t * 524288;
            short* scW = p.scB + (size_t)(t + 1) * 262144;
            for (unsigned u = slot; u < 128; u += NSLOT) {
                int br = (int)(u >> 6);
                int rem = (int)(u & 63);
                int mt = rem >> 1;           // 0..31
                int ctl = rem & 1;           // 0..1
                int ct = (int)g * 2 + ctl;   // 0..15
                int mh = mt * 16;
                const short* A = br ? hq : hp;
                const short* Bsw = br ? p.sw_spr : p.sw_spo;
                const float* bias = br ? p.b_spr : p.b_spo;
                const float* noise = (br ? p.prior_noise : p.post_noise) + (size_t)t * 131072;
                float* mO  = (br ? p.priMeans  : p.postMeans)  + (size_t)t * 131072;
                float* sO  = (br ? p.priStds   : p.postStds)   + (size_t)t * 131072;
                float* stO = (br ? p.priStates : p.postStates) + (size_t)t * 131072;
                int catOff = br ? 256 : 0;
                f32x4 ma = zero4(), sa = zero4();
#pragma unroll 4
                for (int kt = 0; kt < 32; ++kt) {
                    bf16x8 a  = loadA16(A, mh, kt * 32, 1024, lane);
                    bf16x8 bm = loadB16(Bsw, (size_t)ct * 32 + kt, lane);
                    bf16x8 bs = loadB16(Bsw, (size_t)(16 + ct) * 32 + kt, lane);
                    ma = MFMA(a, bm, ma);
                    sa = MFMA(a, bs, sa);
                }
#pragma unroll
                for (int i = 0; i < 4; ++i) {
                    int m = mh + q * 4 + i;
                    int c = ct * 16 + cl;
                    float mean = ma[i] + bias[c];
                    float sd = softplusf_(sa[i] + bias[c + 256]) + 0.1f;
                    float st = mean + sd * noise[(size_t)m * 256 + c];
                    mO[(size_t)m * 256 + c] = mean;
                    sO[(size_t)m * 256 + c] = sd;
                    stO[(size_t)m * 256 + c] = st;
                    stS(&scW[(size_t)m * 512 + catOff + c], f2bf(st));
                }
            }
        }
        hbar(p.bar, g, P, rank, &bc);
    }
}

// ---------------------------------------------------------------------------
// Fallback per-phase kernels (used only if cooperative launch is rejected).
// ---------------------------------------------------------------------------
__global__ __launch_bounds__(256) void k_embed_state(
    const short* __restrict__ A, const short* __restrict__ Bsw,
    const float* __restrict__ bias, short* __restrict__ outBf)
{
    int wid = threadIdx.x >> 6;
    int lane = threadIdx.x & 63;
    int nt = blockIdx.x & 63, mb = blockIdx.x >> 6;
    int m0 = (mb * 4 + wid) * 32;
    f32x4 acc0 = zero4(), acc1 = zero4();
#pragma unroll 4
    for (int kt = 0; kt < 16; ++kt) {
        bf16x8 a0 = loadA16(A, m0,      kt * 32, 512, lane);
        bf16x8 a1 = loadA16(A, m0 + 16, kt * 32, 512, lane);
        bf16x8 b  = loadB16(Bsw, (size_t)nt * 16 + kt, lane);
        acc0 = MFMA(a0, b, acc0);
        acc1 = MFMA(a1, b, acc1);
    }
    int q = lane >> 4, cl = lane & 15;
    int n = nt * 16 + cl;
    float bn = bias[n];
#pragma unroll
    for (int i = 0; i < 4; ++i) {
        int m = m0 + q * 4 + i;
        outBf[(size_t)m * 1024 + n]        = f2bf(fmaxf(acc0[i] + bn, 0.f));
        outBf[(size_t)(m + 16) * 1024 + n] = f2bf(fmaxf(acc1[i] + bn, 0.f));
    }
}

__global__ __launch_bounds__(256) void k_gru(
    const short* __restrict__ Hbf, const short* __restrict__ Pbf,
    const float* __restrict__ Pf32,
    const short* __restrict__ sw_ih, const short* __restrict__ sw_hh,
    const float* __restrict__ b_ih, const float* __restrict__ b_hh,
    float* __restrict__ belF32, short* __restrict__ belBf)
{
    int wid = threadIdx.x >> 6;
    int lane = threadIdx.x & 63;
    int nt = blockIdx.x & 63, mb = blockIdx.x >> 6;
    int m0 = (mb * 4 + wid) * 32;
    f32x4 r0 = zero4(), r1 = zero4(), z0 = zero4(), z1 = zero4();
    f32x4 ni0 = zero4(), ni1 = zero4(), nh0 = zero4(), nh1 = zero4();
#pragma unroll 4
    for (int kt = 0; kt < 32; ++kt) {
        bf16x8 a0 = loadA16(Hbf, m0,      kt * 32, 1024, lane);
        bf16x8 a1 = loadA16(Hbf, m0 + 16, kt * 32, 1024, lane);
        bf16x8 br = loadB16(sw_ih, (size_t)(0 * 64 + nt) * 32 + kt, lane);
        bf16x8 bz = loadB16(sw_ih, (size_t)(1 * 64 + nt) * 32 + kt, lane);
        bf16x8 bn = loadB16(sw_ih, (size_t)(2 * 64 + nt) * 32 + kt, lane);
        r0 = MFMA(a0, br, r0);   r1 = MFMA(a1, br, r1);
        z0 = MFMA(a0, bz, z0);   z1 = MFMA(a1, bz, z1);
        ni0 = MFMA(a0, bn, ni0); ni1 = MFMA(a1, bn, ni1);
    }
#pragma unroll 4
    for (int kt = 0; kt < 32; ++kt) {
        bf16x8 a0 = loadA16(Pbf, m0,      kt * 32, 1024, lane);
        bf16x8 a1 = loadA16(Pbf, m0 + 16, kt * 32, 1024, lane);
        bf16x8 br = loadB16(sw_hh, (size_t)(0 * 64 + nt) * 32 + kt, lane);
        bf16x8 bz = loadB16(sw_hh, (size_t)(1 * 64 + nt) * 32 + kt, lane);
        bf16x8 bn = loadB16(sw_hh, (size_t)(2 * 64 + nt) * 32 + kt, lane);
        r0 = MFMA(a0, br, r0);   r1 = MFMA(a1, br, r1);
        z0 = MFMA(a0, bz, z0);   z1 = MFMA(a1, bz, z1);
        nh0 = MFMA(a0, bn, nh0); nh1 = MFMA(a1, bn, nh1);
    }
    int q = lane >> 4, cl = lane & 15;
    int n = nt * 16 + cl;
    float bihr = b_ih[n] + b_hh[n];
    float bihz = b_ih[1024 + n] + b_hh[1024 + n];
    float bin = b_ih[2048 + n], bhn = b_hh[2048 + n];
#pragma unroll
    for (int f = 0; f < 2; ++f) {
#pragma unroll
        for (int i = 0; i < 4; ++i) {
            int m = m0 + f * 16 + q * 4 + i;
            float rv = f ? r1[i] : r0[i];
            float zv = f ? z1[i] : z0[i];
            float niv = f ? ni1[i] : ni0[i];
            float nhv = f ? nh1[i] : nh0[i];
            float rr = sigmoidf_(rv + bihr);
            float zz = sigmoidf_(zv + bihz);
            float ng = tanhf(niv + bin + rr * (nhv + bhn));
            float h = Pf32[(size_t)m * 1024 + n];
            float v = (1.f - zz) * ng + zz * h;
            belF32[(size_t)m * 1024 + n] = v;
            belBf[(size_t)m * 1024 + n] = f2bf(v);
        }
    }
}

__global__ __launch_bounds__(256) void k_pp(
    const short* __restrict__ Bel, const short* __restrict__ ObsBf,
    const float* __restrict__ Pose,
    const short* __restrict__ sw_ebpo, const short* __restrict__ sw_ebpr,
    const float* __restrict__ Wf_ebpr,
    const float* __restrict__ b_ebpo, const float* __restrict__ b_ebpr,
    short* __restrict__ hpBf, short* __restrict__ hqBf)
{
    int wid = threadIdx.x >> 6;
    int lane = threadIdx.x & 63;
    int q = lane >> 4, cl = lane & 15;
    int b = blockIdx.x;
    if (b < 256) {
        int nt = b & 63, mb = b >> 6;
        int m0 = (mb * 4 + wid) * 32;
        f32x4 acc0 = zero4(), acc1 = zero4();
#pragma unroll 4
        for (int kt = 0; kt < 32; ++kt) {
            bf16x8 a0 = loadA16(Bel, m0,      kt * 32, 1024, lane);
            bf16x8 a1 = loadA16(Bel, m0 + 16, kt * 32, 1024, lane);
            bf16x8 bb = loadB16(sw_ebpo, (size_t)nt * 64 + kt, lane);
            acc0 = MFMA(a0, bb, acc0);
            acc1 = MFMA(a1, bb, acc1);
        }
#pragma unroll 4
        for (int kt = 32; kt < 64; ++kt) {
            bf16x8 a0 = loadA16(ObsBf, m0,      (kt - 32) * 32, 1024, lane);
            bf16x8 a1 = loadA16(ObsBf, m0 + 16, (kt - 32) * 32, 1024, lane);
            bf16x8 bb = loadB16(sw_ebpo, (size_t)nt * 64 + kt, lane);
            acc0 = MFMA(a0, bb, acc0);
            acc1 = MFMA(a1, bb, acc1);
        }
        int n = nt * 16 + cl;
        float bn = b_ebpo[n];
#pragma unroll
        for (int i = 0; i < 4; ++i) {
            int m = m0 + q * 4 + i;
            hpBf[(size_t)m * 1024 + n]        = f2bf(fmaxf(acc0[i] + bn, 0.f));
            hpBf[(size_t)(m + 16) * 1024 + n] = f2bf(fmaxf(acc1[i] + bn, 0.f));
        }
    } else {
        int b2 = b - 256;
        int nt = b2 & 63, mb = b2 >> 6;
        int m0 = (mb * 4 + wid) * 32;
        f32x4 acc0 = zero4(), acc1 = zero4();
#pragma unroll 4
        for (int kt = 0; kt < 32; ++kt) {
            bf16x8 a0 = loadA16(Bel, m0,      kt * 32, 1024, lane);
            bf16x8 a1 = loadA16(Bel, m0 + 16, kt * 32, 1024, lane);
            bf16x8 bb = loadB16(sw_ebpr, (size_t)nt * 32 + kt, lane);
            acc0 = MFMA(a0, bb, acc0);
            acc1 = MFMA(a1, bb, acc1);
        }
        int n = nt * 16 + cl;
        float bn = b_ebpr[n];
#pragma unroll
        for (int f = 0; f < 2; ++f) {
#pragma unroll
            for (int i = 0; i < 4; ++i) {
                int m = m0 + f * 16 + q * 4 + i;
                float v = (f ? acc1[i] : acc0[i]) + bn;
#pragma unroll
                for (int pp = 0; pp < 6; ++pp)
                    v += Pose[(size_t)m * 6 + pp] * Wf_ebpr[(size_t)(1024 + pp) * 1024 + n];
                hqBf[(size_t)m * 1024 + n] = f2bf(fmaxf(v, 0.f));
            }
        }
    }
}

__global__ __launch_bounds__(256) void k_head(
    const short* __restrict__ Hp, const short* __restrict__ Hq,
    const short* __restrict__ sw_spo, const short* __restrict__ sw_spr,
    const float* __restrict__ b_spo, const float* __restrict__ b_spr,
    const float* __restrict__ nPost, const float* __restrict__ nPri,
    float* __restrict__ pM, float* __restrict__ pS, float* __restrict__ pSt,
    float* __restrict__ qM, float* __restrict__ qS, float* __restrict__ qSt,
    short* __restrict__ stateCat)
{
    int gw = blockIdx.x * 4 + (threadIdx.x >> 6);
    int lane = threadIdx.x & 63;
    int br = gw >> 9, rem = gw & 511;
    int mt = rem >> 4, ct = rem & 15;
    int m0 = mt * 16;
    const short* A = br ? Hq : Hp;
    const short* Bsw = br ? sw_spr : sw_spo;
    const float* bias = br ? b_spr : b_spo;
    const float* noise = br ? nPri : nPost;
    float* mO = br ? qM : pM;
    float* sO = br ? qS : pS;
    float* stO = br ? qSt : pSt;
    int catOff = br ? 256 : 0;
    f32x4 ma = zero4(), sa = zero4();
#pragma unroll 4
    for (int kt = 0; kt < 32; ++kt) {
        bf16x8 a = loadA16(A, m0, kt * 32, 1024, lane);
        bf16x8 bm = loadB16(Bsw, (size_t)ct * 32 + kt, lane);
        bf16x8 bs = loadB16(Bsw, (size_t)(16 + ct) * 32 + kt, lane);
        ma = MFMA(a, bm, ma);
        sa = MFMA(a, bs, sa);
    }
    int q = lane >> 4, cl = lane & 15;
#pragma unroll
    for (int i = 0; i < 4; ++i) {
        int m = m0 + q * 4 + i;
        int c = ct * 16 + cl;
        float mean = ma[i] + bias[c];
        float sd = softplusf_(sa[i] + bias[c + 256]) + 0.1f;
        float st = mean + sd * noise[(size_t)m * 256 + c];
        mO[(size_t)m * 256 + c] = mean;
        sO[(size_t)m * 256 + c] = sd;
        stO[(size_t)m * 256 + c] = st;
        stateCat[(size_t)m * 512 + catOff + c] = f2bf(st);
    }
}

// ---------------------------------------------------------------------------
extern "C" void kernel_launch(void* const* d_in, const int* in_sizes, int n_in,
                              void* d_out, int out_size, void* d_ws, size_t ws_size,
                              hipStream_t stream)
{
    const float* prev_state  = (const float*)d_in[0];
    const float* prev_belief = (const float*)d_in[1];
    const float* poses       = (const float*)d_in[2];
    const float* obs         = (const float*)d_in[3];
    const float* post_noise  = (const float*)d_in[4];
    const float* prior_noise = (const float*)d_in[5];
    const float* w_es   = (const float*)d_in[6];
    const float* b_es   = (const float*)d_in[7];
    const float* w_ih   = (const float*)d_in[8];
    const float* w_hh   = (const float*)d_in[9];
    const float* b_ih   = (const float*)d_in[10];
    const float* b_hh   = (const float*)d_in[11];
    const float* w_ebpo = (const float*)d_in[12];
    const float* b_ebpo = (const float*)d_in[13];
    const float* w_spo  = (const float*)d_in[14];
    const float* b_spo  = (const float*)d_in[15];
    const float* w_ebpr = (const float*)d_in[16];
    const float* b_ebpr = (const float*)d_in[17];
    const float* w_spr  = (const float*)d_in[18];
    const float* b_spr  = (const float*)d_in[19];

    float* out = (float*)d_out;
    float* beliefs    = out;
    float* priStates  = out + 16777216;
    float* priMeans   = out + 20971520;
    float* priStds    = out + 25165824;
    float* postStates = out + 29360128;
    float* postMeans  = out + 33554432;
    float* postStds   = out + 37748736;

    short* ws = (short*)d_ws;
    size_t o = 0;
    short* sw_es   = ws + o; o += (size_t)512 * 1024;
    short* sw_ih   = ws + o; o += (size_t)1024 * 3072;
    short* sw_hh   = ws + o; o += (size_t)1024 * 3072;
    short* sw_ebpo = ws + o; o += (size_t)2048 * 1024;
    short* sw_ebpr = ws + o; o += (size_t)1024 * 1024;
    short* sw_spo  = ws + o; o += (size_t)1024 * 512;
    short* sw_spr  = ws + o; o += (size_t)1024 * 512;
    short* obsBf   = ws + o; o += (size_t)32 * 512 * 1024;
    short* hiddenB = ws + o; o += (size_t)32 * 512 * 1024;   // per-step
    short* belInit = ws + o; o += (size_t)512 * 1024;
    short* belB    = ws + o; o += (size_t)32 * 512 * 1024;   // per-step
    short* hpB     = ws + o; o += (size_t)32 * 512 * 1024;   // per-step
    short* hqB     = ws + o; o += (size_t)32 * 512 * 1024;   // per-step
    short* scB     = ws + o; o += (size_t)33 * 512 * 512;    // per-step (t=0..32)
    unsigned* bar  = (unsigned*)(ws + o); o += 8192;         // 4096 u32

    // ---- pre-pass ----
    k_swizzle<<<dim3(256),  dim3(256), 0, stream>>>(w_es,   sw_es,   16, 1024);
    k_swizzle<<<dim3(1536), dim3(256), 0, stream>>>(w_ih,   sw_ih,   32, 3072);
    k_swizzle<<<dim3(1536), dim3(256), 0, stream>>>(w_hh,   sw_hh,   32, 3072);
    k_swizzle<<<dim3(1024), dim3(256), 0, stream>>>(w_ebpo, sw_ebpo, 64, 1024);
    k_swizzle<<<dim3(512),  dim3(256), 0, stream>>>(w_ebpr, sw_ebpr, 32, 1024);
    k_swizzle<<<dim3(256),  dim3(256), 0, stream>>>(w_spo,  sw_spo,  32, 512);
    k_swizzle<<<dim3(256),  dim3(256), 0, stream>>>(w_spr,  sw_spr,  32, 512);
    k_obs2bf<<<dim3(8192), dim3(256), 0, stream>>>(obs, obsBf);
    k_init<<<dim3(3072), dim3(256), 0, stream>>>(prev_state, prev_belief, scB, belInit, bar);

    // ---- persistent kernel: nt-partitioned, weights L2-resident ----
    RP2 rp;
    rp.sw_es = sw_es; rp.sw_ih = sw_ih; rp.sw_hh = sw_hh;
    rp.sw_ebpo = sw_ebpo; rp.sw_ebpr = sw_ebpr; rp.sw_spo = sw_spo; rp.sw_spr = sw_spr;
    rp.Wf_ebpr = w_ebpr;
    rp.b_es = b_es; rp.b_ih = b_ih; rp.b_hh = b_hh;
    rp.b_ebpo = b_ebpo; rp.b_ebpr = b_ebpr; rp.b_spo = b_spo; rp.b_spr = b_spr;
    rp.prev_belief = prev_belief; rp.poses = poses;
    rp.post_noise = post_noise; rp.prior_noise = prior_noise;
    rp.obsBf = obsBf; rp.belInit = belInit;
    rp.hiddenB = hiddenB; rp.belB = belB; rp.hpB = hpB; rp.hqB = hqB; rp.scB = scB;
    rp.beliefs = beliefs;
    rp.priStates = priStates; rp.priMeans = priMeans; rp.priStds = priStds;
    rp.postStates = postStates; rp.postMeans = postMeans; rp.postStds = postStds;
    rp.bar = bar;

    void* kargs[] = { (void*)&rp };
    hipError_t ce = hipLaunchCooperativeKernel(k_rssm3, dim3(NBLK), dim3(512),
                                               kargs, 0u, stream);
    if (ce != hipSuccess) {
        // fallback: per-phase launch loop (proven path), per-step bufs
        for (int t = 0; t < 32; ++t) {
            const short* belPrevBf = t ? belB + (size_t)(t - 1) * 524288 : belInit;
            short* belCurBf = belB + (size_t)t * 524288;
            const float* belPrevF = t ? (beliefs + (size_t)(t - 1) * 524288) : prev_belief;
            float* belT = beliefs + (size_t)t * 524288;
            short* hid = hiddenB + (size_t)t * 524288;
            short* hp = hpB + (size_t)t * 524288;
            short* hq = hqB + (size_t)t * 524288;

            k_embed_state<<<dim3(256), dim3(256), 0, stream>>>(scB + (size_t)t * 262144,
                                                               sw_es, b_es, hid);
            k_gru<<<dim3(256), dim3(256), 0, stream>>>(hid, belPrevBf, belPrevF,
                                                       sw_ih, sw_hh, b_ih, b_hh, belT, belCurBf);
            k_pp<<<dim3(512), dim3(256), 0, stream>>>(belCurBf, obsBf + (size_t)t * 524288,
                                                      poses + (size_t)t * 3072,
                                                      sw_ebpo, sw_ebpr, w_ebpr,
                                                      b_ebpo, b_ebpr, hp, hq);
            k_head<<<dim3(256), dim3(256), 0, stream>>>(hp, hq, sw_spo, sw_spr, b_spo, b_spr,
                                                        post_noise + (size_t)t * 131072,
                                                        prior_noise + (size_t)t * 131072,
                                                        postMeans + (size_t)t * 131072,
                                                        postStds + (size_t)t * 131072,
                                                        postStates + (size_t)t * 131072,
                                                        priMeans + (size_t)t * 131072,
                                                        priStds + (size_t)t * 131072,
                                                        priStates + (size_t)t * 131072,
                                                        scB + (size_t)(t + 1) * 262144);
        }
    }
}

// Round 6
// 2654.782 us; speedup vs baseline: 1.2724x; 1.2715x over previous
//
#include <hip/hip_runtime.h>
#include <math.h>

// ---------------------------------------------------------------------------
// RSSM, Round 8: nt-partitioned persistent kernel, latency-wall edition.
// R7 post-mortem: FETCH fell to 1.25GB (weights L2-resident, as designed) but
// 473 GB/s effective = MALL-latency-bound with only 8 waves/CU.  Fixes:
//   1. 512 blocks x 256 thr (2 blocks/CU, 16 waves/CU) -> 2x outstanding misses
//   2. block's waves share the FAT operand: mt in low bits of unit index so
//      4 waves read the same B-fragments (192KB/unit in GRU) via L1
//   3. phase C merged: one unit does hp+hq, belCur A-frags loaded once
// Census/barrier/store discipline identical to R7 (twice-validated).
// ---------------------------------------------------------------------------

typedef __attribute__((ext_vector_type(8))) short bf16x8;
typedef __attribute__((ext_vector_type(4))) float f32x4;

#define MFMA(a, b, c) __builtin_amdgcn_mfma_f32_16x16x32_bf16(a, b, c, 0, 0, 0)
#define NBLK 512

__device__ __forceinline__ short f2bf(float f) {
    unsigned u = __float_as_uint(f);
    u += 0x7FFF + ((u >> 16) & 1);   // RNE
    return (short)(u >> 16);
}
__device__ __forceinline__ float sigmoidf_(float x) { return 1.f / (1.f + expf(-x)); }
__device__ __forceinline__ float softplusf_(float x) {
    return fmaxf(x, 0.f) + log1pf(expf(-fabsf(x)));
}
__device__ __forceinline__ f32x4 zero4() { f32x4 v = {0.f, 0.f, 0.f, 0.f}; return v; }

// agent-scope (write-through) activation store; relaxed = no fence emitted
__device__ __forceinline__ void stS(short* p, short v) {
    __hip_atomic_store(p, v, __ATOMIC_RELAXED, __HIP_MEMORY_SCOPE_AGENT);
}
__device__ __forceinline__ unsigned ldU(const unsigned* p) {
    return __hip_atomic_load(p, __ATOMIC_RELAXED, __HIP_MEMORY_SCOPE_AGENT);
}

// B-frag pre-swizzle (one wave per 16n x 32k tile)
__global__ __launch_bounds__(256) void k_swizzle(const float* __restrict__ W,
                                                 short* __restrict__ out,
                                                 int KT, int N)
{
    int gw = blockIdx.x * 4 + (threadIdx.x >> 6);
    int lane = threadIdx.x & 63;
    int nt = gw / KT, kt = gw % KT;
    const float* src = W + (size_t)(kt * 32 + (lane >> 4) * 8) * N + nt * 16 + (lane & 15);
    short tmp[8];
#pragma unroll
    for (int j = 0; j < 8; ++j) tmp[j] = f2bf(src[(size_t)j * N]);
    *(bf16x8*)(out + (((size_t)gw * 64 + lane) << 3)) = *(const bf16x8*)tmp;
}

// obs fp32 [32*512*1024] -> bf16
__global__ __launch_bounds__(256) void k_obs2bf(const float* __restrict__ obs,
                                                short* __restrict__ out)
{
    size_t i = ((size_t)blockIdx.x * 256 + threadIdx.x) * 8;
    short tmp[8];
#pragma unroll
    for (int j = 0; j < 8; ++j) tmp[j] = f2bf(obs[i + j]);
    *(bf16x8*)(out + i) = *(const bf16x8*)tmp;
}

// init stateCat[0], belInit, zero barrier region (4096 u32)
__global__ __launch_bounds__(256) void k_init(const float* __restrict__ prev_state,
                                              const float* __restrict__ prev_belief,
                                              short* __restrict__ stateCat0,
                                              short* __restrict__ belInit,
                                              unsigned* __restrict__ bar)
{
    int i = blockIdx.x * 256 + threadIdx.x;
    if (i < 4096) bar[i] = 0u;
    if (i < 262144) {
        int m = i >> 9, c = i & 511;
        stateCat0[i] = f2bf(prev_state[m * 256 + (c & 255)]);
    } else {
        int j = i - 262144;
        belInit[j] = f2bf(prev_belief[j]);
    }
}

__device__ __forceinline__ bf16x8 loadA16(const short* A, int m0, int kelem, int strideElems, int lane) {
    return *(const bf16x8*)(A + (size_t)(m0 + (lane & 15)) * strideElems + kelem + ((lane >> 4) << 3));
}
__device__ __forceinline__ bf16x8 loadB16(const short* Bsw, size_t tileIdx, int lane) {
    return *(const bf16x8*)(Bsw + ((tileIdx * 64 + lane) << 3));
}

// ---------------------------------------------------------------------------
struct RP2 {
    const short *sw_es, *sw_ih, *sw_hh, *sw_ebpo, *sw_ebpr, *sw_spo, *sw_spr;
    const float *Wf_ebpr;
    const float *b_es, *b_ih, *b_hh, *b_ebpo, *b_ebpr, *b_spo, *b_spr;
    const float *prev_belief, *poses, *post_noise, *prior_noise;
    const short *obsBf;
    const short *belInit;
    short *hiddenB, *belB, *hpB, *hqB, *scB;   // per-step buffers
    float *beliefs, *priStates, *priMeans, *priStds, *postStates, *postMeans, *postStds;
    unsigned *bar;  // [0]=rendezvous, [8]=global, [64+g*64]=census, [1024+g*64]=arrive, [2048+g*64]=release
};

// hierarchical fence-free barrier (R7-validated): data drained by
// __syncthreads (vmcnt 0); agent stores already MALL-visible; monotonic cnts.
__device__ __forceinline__ void hbar(unsigned* bar, unsigned g, unsigned P,
                                     unsigned rank, unsigned* bc)
{
    unsigned c = ++(*bc);
    __syncthreads();
    if (threadIdx.x == 0) {
        unsigned* larr = bar + 1024 + g * 64;
        unsigned* lrel = bar + 2048 + g * 64;
        __hip_atomic_fetch_add(larr, 1u, __ATOMIC_RELAXED, __HIP_MEMORY_SCOPE_AGENT);
        if (rank == 0) {
            while (ldU(larr) < c * P) {}
            __hip_atomic_fetch_add(bar + 8, 1u, __ATOMIC_RELAXED, __HIP_MEMORY_SCOPE_AGENT);
            while (ldU(bar + 8) < c * 8u) {}
            __hip_atomic_store(lrel, c, __ATOMIC_RELAXED, __HIP_MEMORY_SCOPE_AGENT);
        } else {
            while (ldU(lrel) < c) {}
        }
    }
    __syncthreads();
}

__global__ __launch_bounds__(256, 2) void k_rssm4(RP2 p)
{
    int wid = threadIdx.x >> 6;          // 0..3
    int lane = threadIdx.x & 63;
    int q = lane >> 4, cl = lane & 15;

    __shared__ unsigned s_g, s_rank, s_P;
    if (threadIdx.x == 0) {
        unsigned x;
        asm volatile("s_getreg_b32 %0, hwreg(HW_REG_XCC_ID)" : "=s"(x));
        x &= 7u;
        s_g = x;
        s_rank = __hip_atomic_fetch_add(p.bar + 64 + x * 64, 1u,
                                        __ATOMIC_RELAXED, __HIP_MEMORY_SCOPE_AGENT);
    }
    __syncthreads();
    if (threadIdx.x == 0) {
        __hip_atomic_fetch_add(p.bar, 1u, __ATOMIC_RELAXED, __HIP_MEMORY_SCOPE_AGENT);
        while (ldU(p.bar) < NBLK) {}
        s_P = ldU(p.bar + 64 + s_g * 64);
    }
    __syncthreads();
    const unsigned g = s_g, P = s_P, rank = s_rank;
    const unsigned NSLOT = P * 4;
    const unsigned slot = rank * 4 + (unsigned)wid;
    unsigned bc = 0;

#pragma unroll 1
    for (int t = 0; t < 32; ++t) {
        // ---- phase A: hidden = relu(stateCat @ w_es + b)  [256 units/XCD] ----
        {
            const short* sc = p.scB + (size_t)t * 262144;
            short* hid = p.hiddenB + (size_t)t * 524288;
            for (unsigned u = slot; u < 256; u += NSLOT) {
                int mt = (int)(u & 31), ntl = (int)(u >> 5);
                int nt = (int)g * 8 + ntl;
                int m0 = mt * 16;
                f32x4 acc = zero4();
#pragma unroll 4
                for (int kt = 0; kt < 16; ++kt) {
                    bf16x8 a = loadA16(sc, m0, kt * 32, 512, lane);
                    bf16x8 b = loadB16(p.sw_es, (size_t)nt * 16 + kt, lane);
                    acc = MFMA(a, b, acc);
                }
                int n = nt * 16 + cl;
                float bn = p.b_es[n];
#pragma unroll
                for (int i = 0; i < 4; ++i)
                    stS(&hid[(size_t)(m0 + q * 4 + i) * 1024 + n],
                        f2bf(fmaxf(acc[i] + bn, 0.f)));
            }
        }
        hbar(p.bar, g, P, rank, &bc);

        // ---- phase B: GRU  [256 units/XCD, waves share B-frags] ----
        {
            const short* hid = p.hiddenB + (size_t)t * 524288;
            const short* belPrevBf = t ? p.belB + (size_t)(t - 1) * 524288 : p.belInit;
            const float* Pf32 = t ? (p.beliefs + (size_t)(t - 1) * 524288) : p.prev_belief;
            float* belT = p.beliefs + (size_t)t * 524288;
            short* belCurBf = p.belB + (size_t)t * 524288;
            for (unsigned u = slot; u < 256; u += NSLOT) {
                int mt = (int)(u & 31), ntl = (int)(u >> 5);
                int nt = (int)g * 8 + ntl;
                int m0 = mt * 16;
                f32x4 r = zero4(), z = zero4(), ni = zero4(), nh = zero4();
#pragma unroll 4
                for (int kt = 0; kt < 32; ++kt) {   // hidden @ w_ih
                    bf16x8 a  = loadA16(hid, m0, kt * 32, 1024, lane);
                    bf16x8 br = loadB16(p.sw_ih, (size_t)(0 * 64 + nt) * 32 + kt, lane);
                    bf16x8 bz = loadB16(p.sw_ih, (size_t)(1 * 64 + nt) * 32 + kt, lane);
                    bf16x8 bn = loadB16(p.sw_ih, (size_t)(2 * 64 + nt) * 32 + kt, lane);
                    r = MFMA(a, br, r);
                    z = MFMA(a, bz, z);
                    ni = MFMA(a, bn, ni);
                }
#pragma unroll 4
                for (int kt = 0; kt < 32; ++kt) {   // beliefPrev @ w_hh
                    bf16x8 a  = loadA16(belPrevBf, m0, kt * 32, 1024, lane);
                    bf16x8 br = loadB16(p.sw_hh, (size_t)(0 * 64 + nt) * 32 + kt, lane);
                    bf16x8 bz = loadB16(p.sw_hh, (size_t)(1 * 64 + nt) * 32 + kt, lane);
                    bf16x8 bn = loadB16(p.sw_hh, (size_t)(2 * 64 + nt) * 32 + kt, lane);
                    r = MFMA(a, br, r);
                    z = MFMA(a, bz, z);
                    nh = MFMA(a, bn, nh);
                }
                int n = nt * 16 + cl;
                float bihr = p.b_ih[n] + p.b_hh[n];
                float bihz = p.b_ih[1024 + n] + p.b_hh[1024 + n];
                float bin = p.b_ih[2048 + n], bhn = p.b_hh[2048 + n];
#pragma unroll
                for (int i = 0; i < 4; ++i) {
                    int m = m0 + q * 4 + i;
                    float rr = sigmoidf_(r[i] + bihr);
                    float zz = sigmoidf_(z[i] + bihz);
                    float ng = tanhf(ni[i] + bin + rr * (nh[i] + bhn));
                    float h = Pf32[(size_t)m * 1024 + n];
                    float v = (1.f - zz) * ng + zz * h;
                    belT[(size_t)m * 1024 + n] = v;          // local-slice readback
                    stS(&belCurBf[(size_t)m * 1024 + n], f2bf(v));
                }
            }
        }
        hbar(p.bar, g, P, rank, &bc);

        // ---- phase C: hp+hq fused  [256 units/XCD, belCur A loaded once] ----
        {
            const short* belCur = p.belB + (size_t)t * 524288;
            const short* obsT = p.obsBf + (size_t)t * 524288;
            const float* poseT = p.poses + (size_t)t * 3072;
            short* hp = p.hpB + (size_t)t * 524288;
            short* hq = p.hqB + (size_t)t * 524288;
            for (unsigned u = slot; u < 256; u += NSLOT) {
                int mt = (int)(u & 31), ntl = (int)(u >> 5);
                int nt = (int)g * 8 + ntl;
                int m0 = mt * 16;
                int n = nt * 16 + cl;
                f32x4 ap = zero4(), aq = zero4();
#pragma unroll 4
                for (int kt = 0; kt < 32; ++kt) {
                    bf16x8 a  = loadA16(belCur, m0, kt * 32, 1024, lane);
                    bf16x8 bp = loadB16(p.sw_ebpo, (size_t)nt * 64 + kt, lane);
                    bf16x8 bq = loadB16(p.sw_ebpr, (size_t)nt * 32 + kt, lane);
                    ap = MFMA(a, bp, ap);
                    aq = MFMA(a, bq, aq);
                }
#pragma unroll 4
                for (int kt = 32; kt < 64; ++kt) {
                    bf16x8 a  = loadA16(obsT, m0, (kt - 32) * 32, 1024, lane);
                    bf16x8 bp = loadB16(p.sw_ebpo, (size_t)nt * 64 + kt, lane);
                    ap = MFMA(a, bp, ap);
                }
                float bnp = p.b_ebpo[n];
                float bnq = p.b_ebpr[n];
#pragma unroll
                for (int i = 0; i < 4; ++i) {
                    int m = m0 + q * 4 + i;
                    stS(&hp[(size_t)m * 1024 + n], f2bf(fmaxf(ap[i] + bnp, 0.f)));
                    float v = aq[i] + bnq;
#pragma unroll
                    for (int pp = 0; pp < 6; ++pp)
                        v += poseT[(size_t)m * 6 + pp] * p.Wf_ebpr[(size_t)(1024 + pp) * 1024 + n];
                    stS(&hq[(size_t)m * 1024 + n], f2bf(fmaxf(v, 0.f)));
                }
            }
        }
        hbar(p.bar, g, P, rank, &bc);

        // ---- phase D: heads  [128 units/XCD] ----
        {
            const short* hp = p.hpB + (size_t)t * 524288;
            const short* hq = p.hqB + (size_t)t * 524288;
            short* scW = p.scB + (size_t)(t + 1) * 262144;
            for (unsigned u = slot; u < 128; u += NSLOT) {
                int mt = (int)(u & 31);
                int ctl = (int)((u >> 5) & 1);
                int br = (int)(u >> 6);
                int ct = (int)g * 2 + ctl;   // 0..15
                int mh = mt * 16;
                const short* A = br ? hq : hp;
                const short* Bsw = br ? p.sw_spr : p.sw_spo;
                const float* bias = br ? p.b_spr : p.b_spo;
                const float* noise = (br ? p.prior_noise : p.post_noise) + (size_t)t * 131072;
                float* mO  = (br ? p.priMeans  : p.postMeans)  + (size_t)t * 131072;
                float* sO  = (br ? p.priStds   : p.postStds)   + (size_t)t * 131072;
                float* stO = (br ? p.priStates : p.postStates) + (size_t)t * 131072;
                int catOff = br ? 256 : 0;
                f32x4 ma = zero4(), sa = zero4();
#pragma unroll 4
                for (int kt = 0; kt < 32; ++kt) {
                    bf16x8 a  = loadA16(A, mh, kt * 32, 1024, lane);
                    bf16x8 bm = loadB16(Bsw, (size_t)ct * 32 + kt, lane);
                    bf16x8 bs = loadB16(Bsw, (size_t)(16 + ct) * 32 + kt, lane);
                    ma = MFMA(a, bm, ma);
                    sa = MFMA(a, bs, sa);
                }
#pragma unroll
                for (int i = 0; i < 4; ++i) {
                    int m = mh + q * 4 + i;
                    int c = ct * 16 + cl;
                    float mean = ma[i] + bias[c];
                    float sd = softplusf_(sa[i] + bias[c + 256]) + 0.1f;
                    float st = mean + sd * noise[(size_t)m * 256 + c];
                    mO[(size_t)m * 256 + c] = mean;
                    sO[(size_t)m * 256 + c] = sd;
                    stO[(size_t)m * 256 + c] = st;
                    stS(&scW[(size_t)m * 512 + catOff + c], f2bf(st));
                }
            }
        }
        hbar(p.bar, g, P, rank, &bc);
    }
}

// ---------------------------------------------------------------------------
// Fallback per-phase kernels (used only if cooperative launch is rejected).
// ---------------------------------------------------------------------------
__global__ __launch_bounds__(256) void k_embed_state(
    const short* __restrict__ A, const short* __restrict__ Bsw,
    const float* __restrict__ bias, short* __restrict__ outBf)
{
    int wid = threadIdx.x >> 6;
    int lane = threadIdx.x & 63;
    int nt = blockIdx.x & 63, mb = blockIdx.x >> 6;
    int m0 = (mb * 4 + wid) * 32;
    f32x4 acc0 = zero4(), acc1 = zero4();
#pragma unroll 4
    for (int kt = 0; kt < 16; ++kt) {
        bf16x8 a0 = loadA16(A, m0,      kt * 32, 512, lane);
        bf16x8 a1 = loadA16(A, m0 + 16, kt * 32, 512, lane);
        bf16x8 b  = loadB16(Bsw, (size_t)nt * 16 + kt, lane);
        acc0 = MFMA(a0, b, acc0);
        acc1 = MFMA(a1, b, acc1);
    }
    int q = lane >> 4, cl = lane & 15;
    int n = nt * 16 + cl;
    float bn = bias[n];
#pragma unroll
    for (int i = 0; i < 4; ++i) {
        int m = m0 + q * 4 + i;
        outBf[(size_t)m * 1024 + n]        = f2bf(fmaxf(acc0[i] + bn, 0.f));
        outBf[(size_t)(m + 16) * 1024 + n] = f2bf(fmaxf(acc1[i] + bn, 0.f));
    }
}

__global__ __launch_bounds__(256) void k_gru(
    const short* __restrict__ Hbf, const short* __restrict__ Pbf,
    const float* __restrict__ Pf32,
    const short* __restrict__ sw_ih, const short* __restrict__ sw_hh,
    const float* __restrict__ b_ih, const float* __restrict__ b_hh,
    float* __restrict__ belF32, short* __restrict__ belBf)
{
    int wid = threadIdx.x >> 6;
    int lane = threadIdx.x & 63;
    int nt = blockIdx.x & 63, mb = blockIdx.x >> 6;
    int m0 = (mb * 4 + wid) * 32;
    f32x4 r0 = zero4(), r1 = zero4(), z0 = zero4(), z1 = zero4();
    f32x4 ni0 = zero4(), ni1 = zero4(), nh0 = zero4(), nh1 = zero4();
#pragma unroll 4
    for (int kt = 0; kt < 32; ++kt) {
        bf16x8 a0 = loadA16(Hbf, m0,      kt * 32, 1024, lane);
        bf16x8 a1 = loadA16(Hbf, m0 + 16, kt * 32, 1024, lane);
        bf16x8 br = loadB16(sw_ih, (size_t)(0 * 64 + nt) * 32 + kt, lane);
        bf16x8 bz = loadB16(sw_ih, (size_t)(1 * 64 + nt) * 32 + kt, lane);
        bf16x8 bn = loadB16(sw_ih, (size_t)(2 * 64 + nt) * 32 + kt, lane);
        r0 = MFMA(a0, br, r0);   r1 = MFMA(a1, br, r1);
        z0 = MFMA(a0, bz, z0);   z1 = MFMA(a1, bz, z1);
        ni0 = MFMA(a0, bn, ni0); ni1 = MFMA(a1, bn, ni1);
    }
#pragma unroll 4
    for (int kt = 0; kt < 32; ++kt) {
        bf16x8 a0 = loadA16(Pbf, m0,      kt * 32, 1024, lane);
        bf16x8 a1 = loadA16(Pbf, m0 + 16, kt * 32, 1024, lane);
        bf16x8 br = loadB16(sw_hh, (size_t)(0 * 64 + nt) * 32 + kt, lane);
        bf16x8 bz = loadB16(sw_hh, (size_t)(1 * 64 + nt) * 32 + kt, lane);
        bf16x8 bn = loadB16(sw_hh, (size_t)(2 * 64 + nt) * 32 + kt, lane);
        r0 = MFMA(a0, br, r0);   r1 = MFMA(a1, br, r1);
        z0 = MFMA(a0, bz, z0);   z1 = MFMA(a1, bz, z1);
        nh0 = MFMA(a0, bn, nh0); nh1 = MFMA(a1, bn, nh1);
    }
    int q = lane >> 4, cl = lane & 15;
    int n = nt * 16 + cl;
    float bihr = b_ih[n] + b_hh[n];
    float bihz = b_ih[1024 + n] + b_hh[1024 + n];
    float bin = b_ih[2048 + n], bhn = b_hh[2048 + n];
#pragma unroll
    for (int f = 0; f < 2; ++f) {
#pragma unroll
        for (int i = 0; i < 4; ++i) {
            int m = m0 + f * 16 + q * 4 + i;
            float rv = f ? r1[i] : r0[i];
            float zv = f ? z1[i] : z0[i];
            float niv = f ? ni1[i] : ni0[i];
            float nhv = f ? nh1[i] : nh0[i];
            float rr = sigmoidf_(rv + bihr);
            float zz = sigmoidf_(zv + bihz);
            float ng = tanhf(niv + bin + rr * (nhv + bhn));
            float h = Pf32[(size_t)m * 1024 + n];
            float v = (1.f - zz) * ng + zz * h;
            belF32[(size_t)m * 1024 + n] = v;
            belBf[(size_t)m * 1024 + n] = f2bf(v);
        }
    }
}

__global__ __launch_bounds__(256) void k_pp(
    const short* __restrict__ Bel, const short* __restrict__ ObsBf,
    const float* __restrict__ Pose,
    const short* __restrict__ sw_ebpo, const short* __restrict__ sw_ebpr,
    const float* __restrict__ Wf_ebpr,
    const float* __restrict__ b_ebpo, const float* __restrict__ b_ebpr,
    short* __restrict__ hpBf, short* __restrict__ hqBf)
{
    int wid = threadIdx.x >> 6;
    int lane = threadIdx.x & 63;
    int q = lane >> 4, cl = lane & 15;
    int b = blockIdx.x;
    if (b < 256) {
        int nt = b & 63, mb = b >> 6;
        int m0 = (mb * 4 + wid) * 32;
        f32x4 acc0 = zero4(), acc1 = zero4();
#pragma unroll 4
        for (int kt = 0; kt < 32; ++kt) {
            bf16x8 a0 = loadA16(Bel, m0,      kt * 32, 1024, lane);
            bf16x8 a1 = loadA16(Bel, m0 + 16, kt * 32, 1024, lane);
            bf16x8 bb = loadB16(sw_ebpo, (size_t)nt * 64 + kt, lane);
            acc0 = MFMA(a0, bb, acc0);
            acc1 = MFMA(a1, bb, acc1);
        }
#pragma unroll 4
        for (int kt = 32; kt < 64; ++kt) {
            bf16x8 a0 = loadA16(ObsBf, m0,      (kt - 32) * 32, 1024, lane);
            bf16x8 a1 = loadA16(ObsBf, m0 + 16, (kt - 32) * 32, 1024, lane);
            bf16x8 bb = loadB16(sw_ebpo, (size_t)nt * 64 + kt, lane);
            acc0 = MFMA(a0, bb, acc0);
            acc1 = MFMA(a1, bb, acc1);
        }
        int n = nt * 16 + cl;
        float bn = b_ebpo[n];
#pragma unroll
        for (int i = 0; i < 4; ++i) {
            int m = m0 + q * 4 + i;
            hpBf[(size_t)m * 1024 + n]        = f2bf(fmaxf(acc0[i] + bn, 0.f));
            hpBf[(size_t)(m + 16) * 1024 + n] = f2bf(fmaxf(acc1[i] + bn, 0.f));
        }
    } else {
        int b2 = b - 256;
        int nt = b2 & 63, mb = b2 >> 6;
        int m0 = (mb * 4 + wid) * 32;
        f32x4 acc0 = zero4(), acc1 = zero4();
#pragma unroll 4
        for (int kt = 0; kt < 32; ++kt) {
            bf16x8 a0 = loadA16(Bel, m0,      kt * 32, 1024, lane);
            bf16x8 a1 = loadA16(Bel, m0 + 16, kt * 32, 1024, lane);
            bf16x8 bb = loadB16(sw_ebpr, (size_t)nt * 32 + kt, lane);
            acc0 = MFMA(a0, bb, acc0);
            acc1 = MFMA(a1, bb, acc1);
        }
        int n = nt * 16 + cl;
        float bn = b_ebpr[n];
#pragma unroll
        for (int f = 0; f < 2; ++f) {
#pragma unroll
            for (int i = 0; i < 4; ++i) {
                int m = m0 + f * 16 + q * 4 + i;
                float v = (f ? acc1[i] : acc0[i]) + bn;
#pragma unroll
                for (int pp = 0; pp < 6; ++pp)
                    v += Pose[(size_t)m * 6 + pp] * Wf_ebpr[(size_t)(1024 + pp) * 1024 + n];
                hqBf[(size_t)m * 1024 + n] = f2bf(fmaxf(v, 0.f));
            }
        }
    }
}

__global__ __launch_bounds__(256) void k_head(
    const short* __restrict__ Hp, const short* __restrict__ Hq,
    const short* __restrict__ sw_spo, const short* __restrict__ sw_spr,
    const float* __restrict__ b_spo, const float* __restrict__ b_spr,
    const float* __restrict__ nPost, const float* __restrict__ nPri,
    float* __restrict__ pM, float* __restrict__ pS, float* __restrict__ pSt,
    float* __restrict__ qM, float* __restrict__ qS, float* __restrict__ qSt,
    short* __restrict__ stateCat)
{
    int gw = blockIdx.x * 4 + (threadIdx.x >> 6);
    int lane = threadIdx.x & 63;
    int br = gw >> 9, rem = gw & 511;
    int mt = rem >> 4, ct = rem & 15;
    int m0 = mt * 16;
    const short* A = br ? Hq : Hp;
    const short* Bsw = br ? sw_spr : sw_spo;
    const float* bias = br ? b_spr : b_spo;
    const float* noise = br ? nPri : nPost;
    float* mO = br ? qM : pM;
    float* sO = br ? qS : pS;
    float* stO = br ? qSt : pSt;
    int catOff = br ? 256 : 0;
    f32x4 ma = zero4(), sa = zero4();
#pragma unroll 4
    for (int kt = 0; kt < 32; ++kt) {
        bf16x8 a = loadA16(A, m0, kt * 32, 1024, lane);
        bf16x8 bm = loadB16(Bsw, (size_t)ct * 32 + kt, lane);
        bf16x8 bs = loadB16(Bsw, (size_t)(16 + ct) * 32 + kt, lane);
        ma = MFMA(a, bm, ma);
        sa = MFMA(a, bs, sa);
    }
    int q = lane >> 4, cl = lane & 15;
#pragma unroll
    for (int i = 0; i < 4; ++i) {
        int m = m0 + q * 4 + i;
        int c = ct * 16 + cl;
        float mean = ma[i] + bias[c];
        float sd = softplusf_(sa[i] + bias[c + 256]) + 0.1f;
        float st = mean + sd * noise[(size_t)m * 256 + c];
        mO[(size_t)m * 256 + c] = mean;
        sO[(size_t)m * 256 + c] = sd;
        stO[(size_t)m * 256 + c] = st;
        stateCat[(size_t)m * 512 + catOff + c] = f2bf(st);
    }
}

// ---------------------------------------------------------------------------
extern "C" void kernel_launch(void* const* d_in, const int* in_sizes, int n_in,
                              void* d_out, int out_size, void* d_ws, size_t ws_size,
                              hipStream_t stream)
{
    const float* prev_state  = (const float*)d_in[0];
    const float* prev_belief = (const float*)d_in[1];
    const float* poses       = (const float*)d_in[2];
    const float* obs         = (const float*)d_in[3];
    const float* post_noise  = (const float*)d_in[4];
    const float* prior_noise = (const float*)d_in[5];
    const float* w_es   = (const float*)d_in[6];
    const float* b_es   = (const float*)d_in[7];
    const float* w_ih   = (const float*)d_in[8];
    const float* w_hh   = (const float*)d_in[9];
    const float* b_ih   = (const float*)d_in[10];
    const float* b_hh   = (const float*)d_in[11];
    const float* w_ebpo = (const float*)d_in[12];
    const float* b_ebpo = (const float*)d_in[13];
    const float* w_spo  = (const float*)d_in[14];
    const float* b_spo  = (const float*)d_in[15];
    const float* w_ebpr = (const float*)d_in[16];
    const float* b_ebpr = (const float*)d_in[17];
    const float* w_spr  = (const float*)d_in[18];
    const float* b_spr  = (const float*)d_in[19];

    float* out = (float*)d_out;
    float* beliefs    = out;
    float* priStates  = out + 16777216;
    float* priMeans   = out + 20971520;
    float* priStds    = out + 25165824;
    float* postStates = out + 29360128;
    float* postMeans  = out + 33554432;
    float* postStds   = out + 37748736;

    short* ws = (short*)d_ws;
    size_t o = 0;
    short* sw_es   = ws + o; o += (size_t)512 * 1024;
    short* sw_ih   = ws + o; o += (size_t)1024 * 3072;
    short* sw_hh   = ws + o; o += (size_t)1024 * 3072;
    short* sw_ebpo = ws + o; o += (size_t)2048 * 1024;
    short* sw_ebpr = ws + o; o += (size_t)1024 * 1024;
    short* sw_spo  = ws + o; o += (size_t)1024 * 512;
    short* sw_spr  = ws + o; o += (size_t)1024 * 512;
    short* obsBf   = ws + o; o += (size_t)32 * 512 * 1024;
    short* hiddenB = ws + o; o += (size_t)32 * 512 * 1024;   // per-step
    short* belInit = ws + o; o += (size_t)512 * 1024;
    short* belB    = ws + o; o += (size_t)32 * 512 * 1024;   // per-step
    short* hpB     = ws + o; o += (size_t)32 * 512 * 1024;   // per-step
    short* hqB     = ws + o; o += (size_t)32 * 512 * 1024;   // per-step
    short* scB     = ws + o; o += (size_t)33 * 512 * 512;    // per-step (t=0..32)
    unsigned* bar  = (unsigned*)(ws + o); o += 8192;         // 4096 u32

    // ---- pre-pass ----
    k_swizzle<<<dim3(256),  dim3(256), 0, stream>>>(w_es,   sw_es,   16, 1024);
    k_swizzle<<<dim3(1536), dim3(256), 0, stream>>>(w_ih,   sw_ih,   32, 3072);
    k_swizzle<<<dim3(1536), dim3(256), 0, stream>>>(w_hh,   sw_hh,   32, 3072);
    k_swizzle<<<dim3(1024), dim3(256), 0, stream>>>(w_ebpo, sw_ebpo, 64, 1024);
    k_swizzle<<<dim3(512),  dim3(256), 0, stream>>>(w_ebpr, sw_ebpr, 32, 1024);
    k_swizzle<<<dim3(256),  dim3(256), 0, stream>>>(w_spo,  sw_spo,  32, 512);
    k_swizzle<<<dim3(256),  dim3(256), 0, stream>>>(w_spr,  sw_spr,  32, 512);
    k_obs2bf<<<dim3(8192), dim3(256), 0, stream>>>(obs, obsBf);
    k_init<<<dim3(3072), dim3(256), 0, stream>>>(prev_state, prev_belief, scB, belInit, bar);

    // ---- persistent kernel: nt-partitioned, 512 blocks for MLP ----
    RP2 rp;
    rp.sw_es = sw_es; rp.sw_ih = sw_ih; rp.sw_hh = sw_hh;
    rp.sw_ebpo = sw_ebpo; rp.sw_ebpr = sw_ebpr; rp.sw_spo = sw_spo; rp.sw_spr = sw_spr;
    rp.Wf_ebpr = w_ebpr;
    rp.b_es = b_es; rp.b_ih = b_ih; rp.b_hh = b_hh;
    rp.b_ebpo = b_ebpo; rp.b_ebpr = b_ebpr; rp.b_spo = b_spo; rp.b_spr = b_spr;
    rp.prev_belief = prev_belief; rp.poses = poses;
    rp.post_noise = post_noise; rp.prior_noise = prior_noise;
    rp.obsBf = obsBf; rp.belInit = belInit;
    rp.hiddenB = hiddenB; rp.belB = belB; rp.hpB = hpB; rp.hqB = hqB; rp.scB = scB;
    rp.beliefs = beliefs;
    rp.priStates = priStates; rp.priMeans = priMeans; rp.priStds = priStds;
    rp.postStates = postStates; rp.postMeans = postMeans; rp.postStds = postStds;
    rp.bar = bar;

    void* kargs[] = { (void*)&rp };
    hipError_t ce = hipLaunchCooperativeKernel(k_rssm4, dim3(NBLK), dim3(256),
                                               kargs, 0u, stream);
    if (ce != hipSuccess) {
        // fallback: per-phase launch loop (proven path), per-step bufs
        for (int t = 0; t < 32; ++t) {
            const short* belPrevBf = t ? belB + (size_t)(t - 1) * 524288 : belInit;
            short* belCurBf = belB + (size_t)t * 524288;
            const float* belPrevF = t ? (beliefs + (size_t)(t - 1) * 524288) : prev_belief;
            float* belT = beliefs + (size_t)t * 524288;
            short* hid = hiddenB + (size_t)t * 524288;
            short* hp = hpB + (size_t)t * 524288;
            short* hq = hqB + (size_t)t * 524288;

            k_embed_state<<<dim3(256), dim3(256), 0, stream>>>(scB + (size_t)t * 262144,
                                                               sw_es, b_es, hid);
            k_gru<<<dim3(256), dim3(256), 0, stream>>>(hid, belPrevBf, belPrevF,
                                                       sw_ih, sw_hh, b_ih, b_hh, belT, belCurBf);
            k_pp<<<dim3(512), dim3(256), 0, stream>>>(belCurBf, obsBf + (size_t)t * 524288,
                                                      poses + (size_t)t * 3072,
                                                      sw_ebpo, sw_ebpr, w_ebpr,
                                                      b_ebpo, b_ebpr, hp, hq);
            k_head<<<dim3(256), dim3(256), 0, stream>>>(hp, hq, sw_spo, sw_spr, b_spo, b_spr,
                                                        post_noise + (size_t)t * 131072,
                                                        prior_noise + (size_t)t * 131072,
                                                        postMeans + (size_t)t * 131072,
                                                        postStds + (size_t)t * 131072,
                                                        postStates + (size_t)t * 131072,
                                                        priMeans + (size_t)t * 131072,
                                                        priStds + (size_t)t * 131072,
                                                        priStates + (size_t)t * 131072,
                                                        scB + (size_t)(t + 1) * 262144);
        }
    }
}